// Round 1
// baseline (887.611 us; speedup 1.0000x reference)
//
#include <hip/hip_runtime.h>
#include <math.h>

#define N_NODES 80000
#define N_EDGES 1280000

__device__ __forceinline__ float leaky(float x) { return x >= 0.f ? x : 0.01f * x; }

// ---------------- setup kernels ----------------

__global__ void k_zero(int* deg, float* bnsums) {
    int i = blockIdx.x * blockDim.x + threadIdx.x;
    if (i < N_NODES) deg[i] = 0;
    if (i < 384) bnsums[i] = 0.f;
}

__global__ void k_deg(const int* __restrict__ ei, int* __restrict__ deg) {
    int e = blockIdx.x * blockDim.x + threadIdx.x;
    if (e < N_EDGES) {
        int dst = ei[N_EDGES + e];
        atomicAdd(&deg[dst], 1);
    }
}

// per-block partial sums of deg + dinv computation
__global__ void k_scanA(const int* __restrict__ deg, int* __restrict__ partial,
                        float* __restrict__ dinv) {
    __shared__ int s[256];
    int t = threadIdx.x;
    int i = blockIdx.x * 256 + t;
    int v = (i < N_NODES) ? deg[i] : 0;
    if (i < N_NODES) dinv[i] = rsqrtf((float)v + 2.0f);  // + self-loop weight 2
    s[t] = v;
    __syncthreads();
    for (int off = 128; off > 0; off >>= 1) {
        if (t < off) s[t] += s[t + off];
        __syncthreads();
    }
    if (t == 0) partial[blockIdx.x] = s[0];
}

// exclusive scan of <=512 block partials, in place
__global__ void k_scanB(int* partial, int nb) {
    __shared__ int s[512];
    int t = threadIdx.x;
    int v = (t < nb) ? partial[t] : 0;
    s[t] = v;
    __syncthreads();
    for (int off = 1; off < 512; off <<= 1) {
        int x = (t >= off) ? s[t - off] : 0;
        __syncthreads();
        s[t] += x;
        __syncthreads();
    }
    if (t < nb) partial[t] = s[t] - v;  // exclusive
}

// per-block exclusive scan + block offset -> cursor (== row_start)
__global__ void k_scanC(const int* __restrict__ deg, const int* __restrict__ partial,
                        int* __restrict__ cursor) {
    __shared__ int s[256];
    int t = threadIdx.x;
    int i = blockIdx.x * 256 + t;
    int v = (i < N_NODES) ? deg[i] : 0;
    s[t] = v;
    __syncthreads();
    for (int off = 1; off < 256; off <<= 1) {
        int x = (t >= off) ? s[t - off] : 0;
        __syncthreads();
        s[t] += x;
        __syncthreads();
    }
    if (i < N_NODES) cursor[i] = partial[blockIdx.x] + s[t] - v;
}

// bucket edges by dst; cursor[v] ends up == row_end(v); row_start(v) = cursor[v-1]
__global__ void k_scatter(const int* __restrict__ ei, const float* __restrict__ dinv,
                          int* __restrict__ cursor, int* __restrict__ csr_src,
                          float* __restrict__ csr_w) {
    int e = blockIdx.x * blockDim.x + threadIdx.x;
    if (e < N_EDGES) {
        int src = ei[e];
        int dst = ei[N_EDGES + e];
        int p = atomicAdd(&cursor[dst], 1);
        csr_src[p] = src;
        csr_w[p] = dinv[src];
    }
}

// h0 = x @ W0   (x: [N,3], W0: [3,64])
__global__ void k_h0(const float* __restrict__ x, const float* __restrict__ W0,
                     float* __restrict__ h) {
    int tid = blockIdx.x * blockDim.x + threadIdx.x;
    if (tid < N_NODES * 64) {
        int v = tid >> 6, c = tid & 63;
        float x0 = x[v * 3], x1 = x[v * 3 + 1], x2 = x[v * 3 + 2];
        h[tid] = x0 * W0[c] + x1 * W0[64 + c] + x2 * W0[128 + c];
    }
}

// ---------------- per-stage kernels ----------------

// wave-per-node aggregation, C=64 (lane == channel). Fuses GCN bias + self-loop
// term and accumulates BN sum / sumsq.
__global__ void __launch_bounds__(256)
k_agg64(const float* __restrict__ h, const int* __restrict__ cursor,
        const int* __restrict__ csr_src, const float* __restrict__ csr_w,
        const float* __restrict__ dinv, const float* __restrict__ bias,
        float* __restrict__ y, float* __restrict__ bnsum) {
    int lane = threadIdx.x & 63;
    int wid = (blockIdx.x * blockDim.x + threadIdx.x) >> 6;
    int nw = (gridDim.x * blockDim.x) >> 6;
    float bl = bias[lane];
    float bs = 0.f, bss = 0.f;
    for (int v = wid; v < N_NODES; v += nw) {
        int end = cursor[v];
        int start = (v == 0) ? 0 : cursor[v - 1];
        float dv = dinv[v];
        float acc = 0.f;
        for (int e = start; e < end; ++e) {
            int s = csr_src[e];
            float w = csr_w[e];
            acc = fmaf(h[s * 64 + lane], w, acc);
        }
        float hv = h[v * 64 + lane];
        float yv = acc * dv + 2.f * dv * dv * hv + bl;
        y[v * 64 + lane] = yv;
        bs += yv;
        bss += yv * yv;
    }
    __shared__ float s1[256], s2[256];
    s1[threadIdx.x] = bs;
    s2[threadIdx.x] = bss;
    __syncthreads();
    if (threadIdx.x < 64) {
        float t1 = s1[threadIdx.x] + s1[threadIdx.x + 64] + s1[threadIdx.x + 128] + s1[threadIdx.x + 192];
        float t2 = s2[threadIdx.x] + s2[threadIdx.x + 64] + s2[threadIdx.x + 128] + s2[threadIdx.x + 192];
        atomicAdd(&bnsum[threadIdx.x], t1);
        atomicAdd(&bnsum[64 + threadIdx.x], t2);
    }
}

// BN stats -> scale/shift
__global__ void k_stats(const float* __restrict__ bnsum, const float* __restrict__ g,
                        const float* __restrict__ bb, float* __restrict__ scale,
                        float* __restrict__ shift, int C) {
    int c = threadIdx.x;
    if (c < C) {
        float inv_n = 1.0f / (float)N_NODES;
        float mean = bnsum[c] * inv_n;
        float var = bnsum[C + c] * inv_n - mean * mean;
        var = fmaxf(var, 0.f);
        float sc = g[c] * rsqrtf(var + 1e-5f);
        scale[c] = sc;
        shift[c] = bb[c] - mean * sc;
    }
}

// BN apply + maxpool(k=2P+1, pad=P) + leaky + (x @ lw.T + lb) + leaky + @Wnext
// NEXT = 64: write h_next [N,64];  NEXT = 3: write h_next [N,3]
template <int P, int NEXT>
__global__ void __launch_bounds__(256)
k_post64(const float* __restrict__ y, const float* __restrict__ scale,
         const float* __restrict__ shift, const float* __restrict__ lw,
         const float* __restrict__ lb, const float* __restrict__ Wn,
         float* __restrict__ hout) {
    __shared__ float s_lwT[64 * 64];                       // transposed: [j][c]
    __shared__ float s_W[NEXT == 64 ? 64 * 64 : 256];      // next-stage W, row-major
    int t = threadIdx.x;
    for (int k = t; k < 64 * 64; k += 256) {
        int c = k >> 6, j = k & 63;
        s_lwT[j * 64 + c] = lw[k];  // lw is [out c][in j]
    }
    if (NEXT == 64) {
        for (int k = t; k < 64 * 64; k += 256) s_W[k] = Wn[k];
    } else {
        if (t < 64 * 3) s_W[t] = Wn[t];
    }
    __syncthreads();
    int lane = t & 63;
    int wid = (blockIdx.x * blockDim.x + t) >> 6;
    int nw = (gridDim.x * blockDim.x) >> 6;
    float sc = scale[lane], sh = shift[lane], lbv = lb[lane];
    for (int v = wid; v < N_NODES; v += nw) {
        float z = fmaf(y[v * 64 + lane], sc, sh);
        float m = z;
#pragma unroll
        for (int d = 1; d <= P; ++d) {
            float up = __shfl(z, lane + d);
            float dn = __shfl(z, lane - d);
            m = fmaxf(m, (lane + d < 64) ? up : -INFINITY);
            m = fmaxf(m, (lane - d >= 0) ? dn : -INFINITY);
        }
        float a = leaky(m);
        float o = lbv;
#pragma unroll
        for (int j = 0; j < 64; ++j)
            o = fmaf(__shfl(a, j), s_lwT[j * 64 + lane], o);
        o = leaky(o);
        if (NEXT == 64) {
            float hn = 0.f;
#pragma unroll
            for (int j = 0; j < 64; ++j)
                hn = fmaf(__shfl(o, j), s_W[j * 64 + lane], hn);
            hout[v * 64 + lane] = hn;
        } else {
            float r0 = o * s_W[lane * 3 + 0];
            float r1 = o * s_W[lane * 3 + 1];
            float r2 = o * s_W[lane * 3 + 2];
#pragma unroll
            for (int off = 32; off > 0; off >>= 1) {
                r0 += __shfl_xor(r0, off);
                r1 += __shfl_xor(r1, off);
                r2 += __shfl_xor(r2, off);
            }
            if (lane == 0) {
                hout[v * 3 + 0] = r0;
                hout[v * 3 + 1] = r1;
                hout[v * 3 + 2] = r2;
            }
        }
    }
}

// C=3 aggregation, thread-per-node
__global__ void __launch_bounds__(256)
k_agg3(const float* __restrict__ h, const int* __restrict__ cursor,
       const int* __restrict__ csr_src, const float* __restrict__ csr_w,
       const float* __restrict__ dinv, const float* __restrict__ bias,
       float* __restrict__ y, float* __restrict__ bnsum) {
    int v = blockIdx.x * blockDim.x + threadIdx.x;
    float y0 = 0.f, y1 = 0.f, y2 = 0.f;
    bool valid = v < N_NODES;
    if (valid) {
        int end = cursor[v];
        int start = (v == 0) ? 0 : cursor[v - 1];
        float dv = dinv[v];
        float a0 = 0.f, a1 = 0.f, a2 = 0.f;
        for (int e = start; e < end; ++e) {
            int s = csr_src[e];
            float w = csr_w[e];
            a0 = fmaf(h[s * 3 + 0], w, a0);
            a1 = fmaf(h[s * 3 + 1], w, a1);
            a2 = fmaf(h[s * 3 + 2], w, a2);
        }
        float sl = 2.f * dv * dv;
        y0 = a0 * dv + sl * h[v * 3 + 0] + bias[0];
        y1 = a1 * dv + sl * h[v * 3 + 1] + bias[1];
        y2 = a2 * dv + sl * h[v * 3 + 2] + bias[2];
        y[v * 3 + 0] = y0;
        y[v * 3 + 1] = y1;
        y[v * 3 + 2] = y2;
    }
    __shared__ float sm[256];
    float vals[6] = {y0, y1, y2, y0 * y0, y1 * y1, y2 * y2};
    for (int c = 0; c < 6; ++c) {
        sm[threadIdx.x] = valid ? vals[c] : 0.f;
        __syncthreads();
        for (int off = 128; off > 0; off >>= 1) {
            if (threadIdx.x < off) sm[threadIdx.x] += sm[threadIdx.x + off];
            __syncthreads();
        }
        if (threadIdx.x == 0) atomicAdd(&bnsum[c], sm[0]);  // layout [s1_0..2, s2_0..2]
        __syncthreads();
    }
}

// final stage post: BN + pool(3,1) over 3 ch + leaky + 3x3 linear + leaky
__global__ void k_post3(const float* __restrict__ y, const float* __restrict__ scale,
                        const float* __restrict__ shift, const float* __restrict__ lw,
                        const float* __restrict__ lb, float* __restrict__ out) {
    int v = blockIdx.x * blockDim.x + threadIdx.x;
    if (v >= N_NODES) return;
    float z0 = fmaf(y[v * 3 + 0], scale[0], shift[0]);
    float z1 = fmaf(y[v * 3 + 1], scale[1], shift[1]);
    float z2 = fmaf(y[v * 3 + 2], scale[2], shift[2]);
    float p0 = fmaxf(z0, z1);
    float p1 = fmaxf(p0, z2);
    float p2 = fmaxf(z1, z2);
    float a0 = leaky(p0), a1 = leaky(p1), a2 = leaky(p2);
    float o0 = leaky(lb[0] + a0 * lw[0] + a1 * lw[1] + a2 * lw[2]);
    float o1 = leaky(lb[1] + a0 * lw[3] + a1 * lw[4] + a2 * lw[5]);
    float o2 = leaky(lb[2] + a0 * lw[6] + a1 * lw[7] + a2 * lw[8]);
    out[v * 3 + 0] = o0;
    out[v * 3 + 1] = o1;
    out[v * 3 + 2] = o2;
}

// ---------------- launcher ----------------

extern "C" void kernel_launch(void* const* d_in, const int* in_sizes, int n_in,
                              void* d_out, int out_size, void* d_ws, size_t ws_size,
                              hipStream_t stream) {
    const float* x  = (const float*)d_in[0];
    const int*   ei = (const int*)d_in[1];
    const float* w0 = (const float*)d_in[2];
    const float* b0 = (const float*)d_in[3];
    const float* g0 = (const float*)d_in[4];
    const float* bb0 = (const float*)d_in[5];
    const float* lw0 = (const float*)d_in[6];
    const float* lb0 = (const float*)d_in[7];
    const float* w1 = (const float*)d_in[8];
    const float* b1 = (const float*)d_in[9];
    const float* g1 = (const float*)d_in[10];
    const float* bb1 = (const float*)d_in[11];
    const float* lw1 = (const float*)d_in[12];
    const float* lb1 = (const float*)d_in[13];
    const float* w2 = (const float*)d_in[14];
    const float* b2 = (const float*)d_in[15];
    const float* g2 = (const float*)d_in[16];
    const float* bb2 = (const float*)d_in[17];
    const float* lw2 = (const float*)d_in[18];
    const float* lb2 = (const float*)d_in[19];
    float* out = (float*)d_out;

    // workspace layout
    char* w = (char*)d_ws;
    int* deg = (int*)w;            w += (size_t)N_NODES * 4;
    float* dinv = (float*)w;       w += (size_t)N_NODES * 4;
    int* cursor = (int*)w;         w += (size_t)N_NODES * 4;
    int* partial = (int*)w;        w += 512 * 4;
    float* bnsum = (float*)w;      w += 384 * 4;      // stage s at +s*128
    float* ss = (float*)w;         w += 384 * 4;      // scale at +s*128, shift at +s*128+64
    int* csr_src = (int*)w;        w += (size_t)N_EDGES * 4;
    float* csr_w = (float*)w;      w += (size_t)N_EDGES * 4;
    float* hbuf = (float*)w;       w += (size_t)N_NODES * 64 * 4;
    float* ybuf = (float*)w;       w += (size_t)N_NODES * 64 * 4;

    const int EB = (N_EDGES + 255) / 256;
    const int NB = (N_NODES + 255) / 256;  // 313

    // --- graph/CSR setup (shared by all 3 stages) ---
    k_zero<<<NB, 256, 0, stream>>>(deg, bnsum);
    k_deg<<<EB, 256, 0, stream>>>(ei, deg);
    k_scanA<<<NB, 256, 0, stream>>>(deg, partial, dinv);
    k_scanB<<<1, 512, 0, stream>>>(partial, NB);
    k_scanC<<<NB, 256, 0, stream>>>(deg, partial, cursor);
    k_scatter<<<EB, 256, 0, stream>>>(ei, dinv, cursor, csr_src, csr_w);

    // --- stage 0 ---
    k_h0<<<(N_NODES * 64 + 255) / 256, 256, 0, stream>>>(x, w0, hbuf);
    k_agg64<<<2500, 256, 0, stream>>>(hbuf, cursor, csr_src, csr_w, dinv, b0, ybuf, bnsum);
    k_stats<<<1, 64, 0, stream>>>(bnsum, g0, bb0, ss, ss + 64, 64);
    k_post64<1, 64><<<1024, 256, 0, stream>>>(ybuf, ss, ss + 64, lw0, lb0, w1, hbuf);

    // --- stage 1 ---
    k_agg64<<<2500, 256, 0, stream>>>(hbuf, cursor, csr_src, csr_w, dinv, b1, ybuf, bnsum + 128);
    k_stats<<<1, 64, 0, stream>>>(bnsum + 128, g1, bb1, ss + 128, ss + 192, 64);
    k_post64<2, 3><<<1024, 256, 0, stream>>>(ybuf, ss + 128, ss + 192, lw1, lb1, w2, hbuf);

    // --- stage 2 (C=3) ---
    k_agg3<<<NB, 256, 0, stream>>>(hbuf, cursor, csr_src, csr_w, dinv, b2, ybuf, bnsum + 256);
    k_stats<<<1, 64, 0, stream>>>(bnsum + 256, g2, bb2, ss + 256, ss + 320, 3);
    k_post3<<<NB, 256, 0, stream>>>(ybuf, ss + 256, ss + 320, lw2, lb2, out);
}

// Round 2
// 728.541 us; speedup vs baseline: 1.2183x; 1.2183x over previous
//
#include <hip/hip_runtime.h>
#include <math.h>

#define N_NODES 80000
#define N_EDGES 1280000

__device__ __forceinline__ float leaky(float x) { return x >= 0.f ? x : 0.01f * x; }

// ---------------- setup kernels ----------------

__global__ void k_zero(int* deg, float* bnsums) {
    int i = blockIdx.x * blockDim.x + threadIdx.x;
    if (i < N_NODES) deg[i] = 0;
    if (i < 384) bnsums[i] = 0.f;
}

__global__ void k_deg(const int* __restrict__ ei, int* __restrict__ deg) {
    int e = blockIdx.x * blockDim.x + threadIdx.x;
    if (e < N_EDGES) {
        int dst = ei[N_EDGES + e];
        atomicAdd(&deg[dst], 1);
    }
}

// per-block partial sums of deg + dinv computation
__global__ void k_scanA(const int* __restrict__ deg, int* __restrict__ partial,
                        float* __restrict__ dinv) {
    __shared__ int s[256];
    int t = threadIdx.x;
    int i = blockIdx.x * 256 + t;
    int v = (i < N_NODES) ? deg[i] : 0;
    if (i < N_NODES) dinv[i] = rsqrtf((float)v + 2.0f);  // + self-loop weight 2
    s[t] = v;
    __syncthreads();
    for (int off = 128; off > 0; off >>= 1) {
        if (t < off) s[t] += s[t + off];
        __syncthreads();
    }
    if (t == 0) partial[blockIdx.x] = s[0];
}

// exclusive scan of <=512 block partials, in place
__global__ void k_scanB(int* partial, int nb) {
    __shared__ int s[512];
    int t = threadIdx.x;
    int v = (t < nb) ? partial[t] : 0;
    s[t] = v;
    __syncthreads();
    for (int off = 1; off < 512; off <<= 1) {
        int x = (t >= off) ? s[t - off] : 0;
        __syncthreads();
        s[t] += x;
        __syncthreads();
    }
    if (t < nb) partial[t] = s[t] - v;  // exclusive
}

// per-block exclusive scan + block offset -> cursor (== row_start)
__global__ void k_scanC(const int* __restrict__ deg, const int* __restrict__ partial,
                        int* __restrict__ cursor) {
    __shared__ int s[256];
    int t = threadIdx.x;
    int i = blockIdx.x * 256 + t;
    int v = (i < N_NODES) ? deg[i] : 0;
    s[t] = v;
    __syncthreads();
    for (int off = 1; off < 256; off <<= 1) {
        int x = (t >= off) ? s[t - off] : 0;
        __syncthreads();
        s[t] += x;
        __syncthreads();
    }
    if (i < N_NODES) cursor[i] = partial[blockIdx.x] + s[t] - v;
}

// bucket edges by dst into packed (src, w) records; cursor[v] ends as row_end(v)
__global__ void k_scatter(const int* __restrict__ ei, const float* __restrict__ dinv,
                          int* __restrict__ cursor, int2* __restrict__ csr) {
    int e = blockIdx.x * blockDim.x + threadIdx.x;
    if (e < N_EDGES) {
        int src = ei[e];
        int dst = ei[N_EDGES + e];
        int p = atomicAdd(&cursor[dst], 1);
        csr[p] = make_int2(src, __float_as_int(dinv[src]));
    }
}

// h0 = x @ W0   (x: [N,3], W0: [3,64])
__global__ void k_h0(const float* __restrict__ x, const float* __restrict__ W0,
                     float* __restrict__ h) {
    int tid = blockIdx.x * blockDim.x + threadIdx.x;
    if (tid < N_NODES * 64) {
        int v = tid >> 6, c = tid & 63;
        float x0 = x[v * 3], x1 = x[v * 3 + 1], x2 = x[v * 3 + 2];
        h[tid] = x0 * W0[c] + x1 * W0[64 + c] + x2 * W0[128 + c];
    }
}

// ---------------- per-stage kernels ----------------

// wave-per-node aggregation, C=64 (lane == channel). 8-deep MLP unroll.
// Fuses GCN bias + self-loop term and accumulates BN sum / sumsq.
__global__ void __launch_bounds__(256)
k_agg64(const float* __restrict__ h, const int* __restrict__ cursor,
        const int2* __restrict__ csr, const float* __restrict__ dinv,
        const float* __restrict__ bias, float* __restrict__ y,
        float* __restrict__ bnsum) {
    int lane = threadIdx.x & 63;
    int wid = (blockIdx.x * blockDim.x + threadIdx.x) >> 6;
    int nw = (gridDim.x * blockDim.x) >> 6;
    float bl = bias[lane];
    float bs = 0.f, bss = 0.f;
    for (int v = wid; v < N_NODES; v += nw) {
        int end = cursor[v];
        int start = (v == 0) ? 0 : cursor[v - 1];
        float dv = dinv[v];
        float acc = 0.f;
        int e = start;
        for (; e + 8 <= end; e += 8) {
            int2 c[8];
#pragma unroll
            for (int u = 0; u < 8; ++u) c[u] = csr[e + u];
            float vv[8];
#pragma unroll
            for (int u = 0; u < 8; ++u) vv[u] = h[(size_t)c[u].x * 64 + lane];
#pragma unroll
            for (int u = 0; u < 8; ++u) acc = fmaf(vv[u], __int_as_float(c[u].y), acc);
        }
        for (; e < end; ++e) {
            int2 c = csr[e];
            acc = fmaf(h[(size_t)c.x * 64 + lane], __int_as_float(c.y), acc);
        }
        float hv = h[(size_t)v * 64 + lane];
        float yv = acc * dv + 2.f * dv * dv * hv + bl;
        y[(size_t)v * 64 + lane] = yv;
        bs += yv;
        bss += yv * yv;
    }
    __shared__ float s1[256], s2[256];
    s1[threadIdx.x] = bs;
    s2[threadIdx.x] = bss;
    __syncthreads();
    if (threadIdx.x < 64) {
        float t1 = s1[threadIdx.x] + s1[threadIdx.x + 64] + s1[threadIdx.x + 128] + s1[threadIdx.x + 192];
        float t2 = s2[threadIdx.x] + s2[threadIdx.x + 64] + s2[threadIdx.x + 128] + s2[threadIdx.x + 192];
        atomicAdd(&bnsum[threadIdx.x], t1);
        atomicAdd(&bnsum[64 + threadIdx.x], t2);
    }
}

// BN(stats inline) + maxpool(k=2P+1,pad=P) + leaky + (x@lw.T+lb) + leaky + @Wnext
template <int P, int NEXT>
__global__ void __launch_bounds__(256)
k_post64(const float* __restrict__ y, const float* __restrict__ bnsum,
         const float* __restrict__ g, const float* __restrict__ bb,
         const float* __restrict__ lw, const float* __restrict__ lb,
         const float* __restrict__ Wn, float* __restrict__ hout) {
    __shared__ float s_lwT[64 * 64];                       // transposed: [j][c]
    __shared__ float s_W[NEXT == 64 ? 64 * 64 : 256];      // next-stage W, row-major
    int t = threadIdx.x;
    for (int k = t; k < 64 * 64; k += 256) {
        int c = k >> 6, j = k & 63;
        s_lwT[j * 64 + c] = lw[k];  // lw is [out c][in j]
    }
    if (NEXT == 64) {
        for (int k = t; k < 64 * 64; k += 256) s_W[k] = Wn[k];
    } else {
        if (t < 64 * 3) s_W[t] = Wn[t];
    }
    int lane = t & 63;
    // BN scale/shift computed per-thread from raw sums (replaces k_stats launch)
    float inv_n = 1.0f / (float)N_NODES;
    float mean = bnsum[lane] * inv_n;
    float var = fmaxf(bnsum[64 + lane] * inv_n - mean * mean, 0.f);
    float sc = g[lane] * rsqrtf(var + 1e-5f);
    float sh = bb[lane] - mean * sc;
    __syncthreads();
    int wid = (blockIdx.x * blockDim.x + t) >> 6;
    int nw = (gridDim.x * blockDim.x) >> 6;
    float lbv = lb[lane];
    for (int v = wid; v < N_NODES; v += nw) {
        float z = fmaf(y[(size_t)v * 64 + lane], sc, sh);
        float m = z;
#pragma unroll
        for (int d = 1; d <= P; ++d) {
            float up = __shfl(z, lane + d);
            float dn = __shfl(z, lane - d);
            m = fmaxf(m, (lane + d < 64) ? up : -INFINITY);
            m = fmaxf(m, (lane - d >= 0) ? dn : -INFINITY);
        }
        float a = leaky(m);
        float o = lbv;
#pragma unroll
        for (int j = 0; j < 64; ++j)
            o = fmaf(__shfl(a, j), s_lwT[j * 64 + lane], o);
        o = leaky(o);
        if (NEXT == 64) {
            float hn = 0.f;
#pragma unroll
            for (int j = 0; j < 64; ++j)
                hn = fmaf(__shfl(o, j), s_W[j * 64 + lane], hn);
            hout[(size_t)v * 64 + lane] = hn;
        } else {
            float r0 = o * s_W[lane * 3 + 0];
            float r1 = o * s_W[lane * 3 + 1];
            float r2 = o * s_W[lane * 3 + 2];
#pragma unroll
            for (int off = 32; off > 0; off >>= 1) {
                r0 += __shfl_xor(r0, off);
                r1 += __shfl_xor(r1, off);
                r2 += __shfl_xor(r2, off);
            }
            if (lane == 0) {
                hout[v * 3 + 0] = r0;
                hout[v * 3 + 1] = r1;
                hout[v * 3 + 2] = r2;
            }
        }
    }
}

// C=3 aggregation, thread-per-node, 4-deep MLP unroll
__global__ void __launch_bounds__(256)
k_agg3(const float* __restrict__ h, const int* __restrict__ cursor,
       const int2* __restrict__ csr, const float* __restrict__ dinv,
       const float* __restrict__ bias, float* __restrict__ y,
       float* __restrict__ bnsum) {
    int v = blockIdx.x * blockDim.x + threadIdx.x;
    float y0 = 0.f, y1 = 0.f, y2 = 0.f;
    bool valid = v < N_NODES;
    if (valid) {
        int end = cursor[v];
        int start = (v == 0) ? 0 : cursor[v - 1];
        float dv = dinv[v];
        float a0 = 0.f, a1 = 0.f, a2 = 0.f;
        int e = start;
        for (; e + 4 <= end; e += 4) {
            int2 c[4];
#pragma unroll
            for (int u = 0; u < 4; ++u) c[u] = csr[e + u];
#pragma unroll
            for (int u = 0; u < 4; ++u) {
                float w = __int_as_float(c[u].y);
                int s = c[u].x;
                a0 = fmaf(h[s * 3 + 0], w, a0);
                a1 = fmaf(h[s * 3 + 1], w, a1);
                a2 = fmaf(h[s * 3 + 2], w, a2);
            }
        }
        for (; e < end; ++e) {
            int2 c = csr[e];
            float w = __int_as_float(c.y);
            int s = c.x;
            a0 = fmaf(h[s * 3 + 0], w, a0);
            a1 = fmaf(h[s * 3 + 1], w, a1);
            a2 = fmaf(h[s * 3 + 2], w, a2);
        }
        float sl = 2.f * dv * dv;
        y0 = a0 * dv + sl * h[v * 3 + 0] + bias[0];
        y1 = a1 * dv + sl * h[v * 3 + 1] + bias[1];
        y2 = a2 * dv + sl * h[v * 3 + 2] + bias[2];
        y[v * 3 + 0] = y0;
        y[v * 3 + 1] = y1;
        y[v * 3 + 2] = y2;
    }
    __shared__ float sm[256];
    float vals[6] = {y0, y1, y2, y0 * y0, y1 * y1, y2 * y2};
    for (int c = 0; c < 6; ++c) {
        sm[threadIdx.x] = valid ? vals[c] : 0.f;
        __syncthreads();
        for (int off = 128; off > 0; off >>= 1) {
            if (threadIdx.x < off) sm[threadIdx.x] += sm[threadIdx.x + off];
            __syncthreads();
        }
        if (threadIdx.x == 0) atomicAdd(&bnsum[c], sm[0]);  // layout [s1_0..2, s2_0..2]
        __syncthreads();
    }
}

// final stage post: BN(stats inline) + pool(3,1) over 3 ch + leaky + 3x3 linear + leaky
__global__ void k_post3(const float* __restrict__ y, const float* __restrict__ bnsum,
                        const float* __restrict__ g, const float* __restrict__ bb,
                        const float* __restrict__ lw, const float* __restrict__ lb,
                        float* __restrict__ out) {
    int v = blockIdx.x * blockDim.x + threadIdx.x;
    if (v >= N_NODES) return;
    float inv_n = 1.0f / (float)N_NODES;
    float sc[3], sh[3];
#pragma unroll
    for (int c = 0; c < 3; ++c) {
        float mean = bnsum[c] * inv_n;
        float var = fmaxf(bnsum[3 + c] * inv_n - mean * mean, 0.f);
        sc[c] = g[c] * rsqrtf(var + 1e-5f);
        sh[c] = bb[c] - mean * sc[c];
    }
    float z0 = fmaf(y[v * 3 + 0], sc[0], sh[0]);
    float z1 = fmaf(y[v * 3 + 1], sc[1], sh[1]);
    float z2 = fmaf(y[v * 3 + 2], sc[2], sh[2]);
    float p0 = fmaxf(z0, z1);
    float p1 = fmaxf(p0, z2);
    float p2 = fmaxf(z1, z2);
    float a0 = leaky(p0), a1 = leaky(p1), a2 = leaky(p2);
    float o0 = leaky(lb[0] + a0 * lw[0] + a1 * lw[1] + a2 * lw[2]);
    float o1 = leaky(lb[1] + a0 * lw[3] + a1 * lw[4] + a2 * lw[5]);
    float o2 = leaky(lb[2] + a0 * lw[6] + a1 * lw[7] + a2 * lw[8]);
    out[v * 3 + 0] = o0;
    out[v * 3 + 1] = o1;
    out[v * 3 + 2] = o2;
}

// ---------------- launcher ----------------

extern "C" void kernel_launch(void* const* d_in, const int* in_sizes, int n_in,
                              void* d_out, int out_size, void* d_ws, size_t ws_size,
                              hipStream_t stream) {
    const float* x  = (const float*)d_in[0];
    const int*   ei = (const int*)d_in[1];
    const float* w0 = (const float*)d_in[2];
    const float* b0 = (const float*)d_in[3];
    const float* g0 = (const float*)d_in[4];
    const float* bb0 = (const float*)d_in[5];
    const float* lw0 = (const float*)d_in[6];
    const float* lb0 = (const float*)d_in[7];
    const float* w1 = (const float*)d_in[8];
    const float* b1 = (const float*)d_in[9];
    const float* g1 = (const float*)d_in[10];
    const float* bb1 = (const float*)d_in[11];
    const float* lw1 = (const float*)d_in[12];
    const float* lb1 = (const float*)d_in[13];
    const float* w2 = (const float*)d_in[14];
    const float* b2 = (const float*)d_in[15];
    const float* g2 = (const float*)d_in[16];
    const float* bb2 = (const float*)d_in[17];
    const float* lw2 = (const float*)d_in[18];
    const float* lb2 = (const float*)d_in[19];
    float* out = (float*)d_out;

    // workspace layout (csr first: needs 8B alignment)
    char* w = (char*)d_ws;
    int2* csr = (int2*)w;          w += (size_t)N_EDGES * 8;
    int* deg = (int*)w;            w += (size_t)N_NODES * 4;
    float* dinv = (float*)w;       w += (size_t)N_NODES * 4;
    int* cursor = (int*)w;         w += (size_t)N_NODES * 4;
    int* partial = (int*)w;        w += 512 * 4;
    float* bnsum = (float*)w;      w += 384 * 4;      // stage s at +s*128
    float* hbuf = (float*)w;       w += (size_t)N_NODES * 64 * 4;
    float* ybuf = (float*)w;       w += (size_t)N_NODES * 64 * 4;

    const int EB = (N_EDGES + 255) / 256;
    const int NB = (N_NODES + 255) / 256;  // 313

    // --- graph/CSR setup (shared by all 3 stages) ---
    k_zero<<<NB, 256, 0, stream>>>(deg, bnsum);
    k_deg<<<EB, 256, 0, stream>>>(ei, deg);
    k_scanA<<<NB, 256, 0, stream>>>(deg, partial, dinv);
    k_scanB<<<1, 512, 0, stream>>>(partial, NB);
    k_scanC<<<NB, 256, 0, stream>>>(deg, partial, cursor);
    k_scatter<<<EB, 256, 0, stream>>>(ei, dinv, cursor, csr);

    // --- stage 0 ---
    k_h0<<<(N_NODES * 64 + 255) / 256, 256, 0, stream>>>(x, w0, hbuf);
    k_agg64<<<2500, 256, 0, stream>>>(hbuf, cursor, csr, dinv, b0, ybuf, bnsum);
    k_post64<1, 64><<<1024, 256, 0, stream>>>(ybuf, bnsum, g0, bb0, lw0, lb0, w1, hbuf);

    // --- stage 1 ---
    k_agg64<<<2500, 256, 0, stream>>>(hbuf, cursor, csr, dinv, b1, ybuf, bnsum + 128);
    k_post64<2, 3><<<1024, 256, 0, stream>>>(ybuf, bnsum + 128, g1, bb1, lw1, lb1, w2, hbuf);

    // --- stage 2 (C=3) ---
    k_agg3<<<NB, 256, 0, stream>>>(hbuf, cursor, csr, dinv, b2, ybuf, bnsum + 256);
    k_post3<<<NB, 256, 0, stream>>>(ybuf, bnsum + 256, g2, bb2, lw2, lb2, out);
}

// Round 3
// 557.902 us; speedup vs baseline: 1.5910x; 1.3059x over previous
//
#include <hip/hip_runtime.h>
#include <hip/hip_bf16.h>
#include <math.h>

#define N_NODES 80000
#define N_EDGES 1280000

typedef __hip_bfloat16 bf16;

__device__ __forceinline__ float leaky(float x) { return x >= 0.f ? x : 0.01f * x; }

// ---------------- setup kernels ----------------

__global__ void k_zero(int* deg, float* bnsums) {
    int i = blockIdx.x * blockDim.x + threadIdx.x;
    if (i < N_NODES) deg[i] = 0;
    if (i < 384) bnsums[i] = 0.f;
}

__global__ void k_deg(const int* __restrict__ ei, int* __restrict__ deg) {
    int e = blockIdx.x * blockDim.x + threadIdx.x;
    if (e < N_EDGES) {
        int dst = ei[N_EDGES + e];
        atomicAdd(&deg[dst], 1);
    }
}

__global__ void k_scanA(const int* __restrict__ deg, int* __restrict__ partial,
                        float* __restrict__ dinv) {
    __shared__ int s[256];
    int t = threadIdx.x;
    int i = blockIdx.x * 256 + t;
    int v = (i < N_NODES) ? deg[i] : 0;
    if (i < N_NODES) dinv[i] = rsqrtf((float)v + 2.0f);  // + self-loop weight 2
    s[t] = v;
    __syncthreads();
    for (int off = 128; off > 0; off >>= 1) {
        if (t < off) s[t] += s[t + off];
        __syncthreads();
    }
    if (t == 0) partial[blockIdx.x] = s[0];
}

__global__ void k_scanB(int* partial, int nb) {
    __shared__ int s[512];
    int t = threadIdx.x;
    int v = (t < nb) ? partial[t] : 0;
    s[t] = v;
    __syncthreads();
    for (int off = 1; off < 512; off <<= 1) {
        int x = (t >= off) ? s[t - off] : 0;
        __syncthreads();
        s[t] += x;
        __syncthreads();
    }
    if (t < nb) partial[t] = s[t] - v;  // exclusive
}

__global__ void k_scanC(const int* __restrict__ deg, const int* __restrict__ partial,
                        int* __restrict__ cursor) {
    __shared__ int s[256];
    int t = threadIdx.x;
    int i = blockIdx.x * 256 + t;
    int v = (i < N_NODES) ? deg[i] : 0;
    s[t] = v;
    __syncthreads();
    for (int off = 1; off < 256; off <<= 1) {
        int x = (t >= off) ? s[t - off] : 0;
        __syncthreads();
        s[t] += x;
        __syncthreads();
    }
    if (i < N_NODES) cursor[i] = partial[blockIdx.x] + s[t] - v;
}

__global__ void k_scatter(const int* __restrict__ ei, const float* __restrict__ dinv,
                          int* __restrict__ cursor, int2* __restrict__ csr) {
    int e = blockIdx.x * blockDim.x + threadIdx.x;
    if (e < N_EDGES) {
        int src = ei[e];
        int dst = ei[N_EDGES + e];
        int p = atomicAdd(&cursor[dst], 1);
        csr[p] = make_int2(src, __float_as_int(dinv[src]));
    }
}

// h0 = x @ W0 (bf16 out)
__global__ void k_h0(const float* __restrict__ x, const float* __restrict__ W0,
                     bf16* __restrict__ h) {
    int tid = blockIdx.x * blockDim.x + threadIdx.x;
    if (tid < N_NODES * 64) {
        int v = tid >> 6, c = tid & 63;
        float x0 = x[v * 3], x1 = x[v * 3 + 1], x2 = x[v * 3 + 2];
        h[tid] = __float2bfloat16(x0 * W0[c] + x1 * W0[64 + c] + x2 * W0[128 + c]);
    }
}

// ---------------- per-stage kernels ----------------

// wave-per-node aggregation, bf16 gathers, 16-deep MLP.
__global__ void __launch_bounds__(256)
k_agg64(const bf16* __restrict__ hb, const int* __restrict__ cursor,
        const int2* __restrict__ csr, const float* __restrict__ dinv,
        const float* __restrict__ bias, float* __restrict__ y,
        float* __restrict__ bnsum) {
    int lane = threadIdx.x & 63;
    int wid = (blockIdx.x * blockDim.x + threadIdx.x) >> 6;
    int nw = (gridDim.x * blockDim.x) >> 6;
    float bl = bias[lane];
    float bs = 0.f, bss = 0.f;
    for (int v = wid; v < N_NODES; v += nw) {
        int end = cursor[v];
        int start = (v == 0) ? 0 : cursor[v - 1];
        float dv = dinv[v];
        float acc = 0.f;
        int e = start;
        for (; e + 16 <= end; e += 16) {
            int2 c[16];
#pragma unroll
            for (int u = 0; u < 16; ++u) c[u] = csr[e + u];
            float vv[16];
#pragma unroll
            for (int u = 0; u < 16; ++u) vv[u] = __bfloat162float(hb[(size_t)c[u].x * 64 + lane]);
#pragma unroll
            for (int u = 0; u < 16; ++u) acc = fmaf(vv[u], __int_as_float(c[u].y), acc);
        }
        for (; e + 4 <= end; e += 4) {
            int2 c[4];
#pragma unroll
            for (int u = 0; u < 4; ++u) c[u] = csr[e + u];
#pragma unroll
            for (int u = 0; u < 4; ++u)
                acc = fmaf(__bfloat162float(hb[(size_t)c[u].x * 64 + lane]), __int_as_float(c[u].y), acc);
        }
        for (; e < end; ++e) {
            int2 c = csr[e];
            acc = fmaf(__bfloat162float(hb[(size_t)c.x * 64 + lane]), __int_as_float(c.y), acc);
        }
        float hv = __bfloat162float(hb[(size_t)v * 64 + lane]);
        float yv = acc * dv + 2.f * dv * dv * hv + bl;
        y[(size_t)v * 64 + lane] = yv;
        bs += yv;
        bss += yv * yv;
    }
    __shared__ float s1[256], s2[256];
    s1[threadIdx.x] = bs;
    s2[threadIdx.x] = bss;
    __syncthreads();
    if (threadIdx.x < 64) {
        float t1 = s1[threadIdx.x] + s1[threadIdx.x + 64] + s1[threadIdx.x + 128] + s1[threadIdx.x + 192];
        float t2 = s2[threadIdx.x] + s2[threadIdx.x + 64] + s2[threadIdx.x + 128] + s2[threadIdx.x + 192];
        atomicAdd(&bnsum[threadIdx.x], t1);
        atomicAdd(&bnsum[64 + threadIdx.x], t2);
    }
}

// BN + maxpool + leaky + (a@lw.T+lb) + leaky [+ @Wn], register-tiled GEMM.
// Block = 128 threads (2 waves); each wave owns a 32-node sub-tile.
// Lane tile: 4 nodes x 8 channels. aT in LDS (stride 36), reused as oT.
template <int P, bool MM2>
__global__ void __launch_bounds__(128)
k_post64(const float* __restrict__ y, const float* __restrict__ bnsum,
         const float* __restrict__ g, const float* __restrict__ bb,
         const float* __restrict__ lw, const float* __restrict__ lb,
         const float* __restrict__ Wn, bf16* __restrict__ hout) {
    __shared__ float s_aT[2][64 * 36];  // per-wave activation tile (transposed), reused as oT
    __shared__ float s_lwT[64 * 64];    // lw transposed: [k][c]
    __shared__ float s_Wn[MM2 ? 64 * 64 : 1];
    int t = threadIdx.x;
    int w = t >> 6, lane = t & 63;
    for (int k0 = t; k0 < 4096; k0 += 128) {
        int kk = k0 >> 6, cc = k0 & 63;
        s_lwT[kk * 64 + cc] = lw[cc * 64 + kk];
        if (MM2) s_Wn[k0] = Wn[k0];
    }
    // BN consts (phase 1: lane == channel)
    float inv_n = 1.0f / (float)N_NODES;
    float mean = bnsum[lane] * inv_n;
    float var = fmaxf(bnsum[64 + lane] * inv_n - mean * mean, 0.f);
    float sc = g[lane] * rsqrtf(var + 1e-5f);
    float sh = bb[lane] - mean * sc;
    // phase-2/3 lane tile coords
    int c0 = (lane >> 3) * 8, n0 = (lane & 7) * 4;
    float lbv[8];
#pragma unroll
    for (int i = 0; i < 8; ++i) lbv[i] = lb[c0 + i];
    float* aT = s_aT[w];

    for (int tile = blockIdx.x; tile < N_NODES / 64; tile += gridDim.x) {
        int nbase = tile * 64 + w * 32;
        __syncthreads();  // protect aT/oT reuse across iterations + weight fill
        // ---- phase 1: load y, BN, pool, leaky -> aT[k][n] ----
#pragma unroll 4
        for (int i = 0; i < 32; ++i) {
            float z = fmaf(y[(size_t)(nbase + i) * 64 + lane], sc, sh);
            float m = z;
#pragma unroll
            for (int d = 1; d <= P; ++d) {
                float up = __shfl(z, lane + d);
                float dn = __shfl(z, lane - d);
                m = fmaxf(m, (lane + d < 64) ? up : -INFINITY);
                m = fmaxf(m, (lane - d >= 0) ? dn : -INFINITY);
            }
            aT[lane * 36 + i] = leaky(m);
        }
        __syncthreads();
        // ---- phase 2: o = leaky(a @ lw.T + lb), 4n x 8c per lane ----
        float acc[4][8];
#pragma unroll
        for (int nn = 0; nn < 4; ++nn)
#pragma unroll
            for (int i = 0; i < 8; ++i) acc[nn][i] = lbv[i];
#pragma unroll 8
        for (int k = 0; k < 64; ++k) {
            float4 av = *(const float4*)&aT[k * 36 + n0];
            float4 w0 = *(const float4*)&s_lwT[k * 64 + c0];
            float4 w1 = *(const float4*)&s_lwT[k * 64 + c0 + 4];
            float a4[4] = {av.x, av.y, av.z, av.w};
            float wv[8] = {w0.x, w0.y, w0.z, w0.w, w1.x, w1.y, w1.z, w1.w};
#pragma unroll
            for (int nn = 0; nn < 4; ++nn)
#pragma unroll
                for (int i = 0; i < 8; ++i) acc[nn][i] = fmaf(a4[nn], wv[i], acc[nn][i]);
        }
#pragma unroll
        for (int nn = 0; nn < 4; ++nn)
#pragma unroll
            for (int i = 0; i < 8; ++i) acc[nn][i] = leaky(acc[nn][i]);

        if (MM2) {
            // write oT (aliases aT; all aT reads completed in program order above)
#pragma unroll
            for (int i = 0; i < 8; ++i) {
                float4 ov = make_float4(acc[0][i], acc[1][i], acc[2][i], acc[3][i]);
                *(float4*)&aT[(c0 + i) * 36 + n0] = ov;
            }
            // ---- phase 3: hn = o @ Wn ----
            float acc2[4][8];
#pragma unroll
            for (int nn = 0; nn < 4; ++nn)
#pragma unroll
                for (int i = 0; i < 8; ++i) acc2[nn][i] = 0.f;
#pragma unroll 8
            for (int k = 0; k < 64; ++k) {
                float4 av = *(const float4*)&aT[k * 36 + n0];
                float4 w0 = *(const float4*)&s_Wn[k * 64 + c0];
                float4 w1 = *(const float4*)&s_Wn[k * 64 + c0 + 4];
                float a4[4] = {av.x, av.y, av.z, av.w};
                float wv[8] = {w0.x, w0.y, w0.z, w0.w, w1.x, w1.y, w1.z, w1.w};
#pragma unroll
                for (int nn = 0; nn < 4; ++nn)
#pragma unroll
                    for (int i = 0; i < 8; ++i) acc2[nn][i] = fmaf(a4[nn], wv[i], acc2[nn][i]);
            }
#pragma unroll
            for (int nn = 0; nn < 4; ++nn) {
                bf16 pk[8];
#pragma unroll
                for (int i = 0; i < 8; ++i) pk[i] = __float2bfloat16(acc2[nn][i]);
                *(uint4*)&hout[(size_t)(nbase + n0 + nn) * 64 + c0] = *(uint4*)pk;
            }
        } else {
            // store o (stage output) directly in bf16
#pragma unroll
            for (int nn = 0; nn < 4; ++nn) {
                bf16 pk[8];
#pragma unroll
                for (int i = 0; i < 8; ++i) pk[i] = __float2bfloat16(acc[nn][i]);
                *(uint4*)&hout[(size_t)(nbase + n0 + nn) * 64 + c0] = *(uint4*)pk;
            }
        }
    }
}

// h3 = o(bf16) @ w2 [64,3] -> fp32 [N,3]
__global__ void __launch_bounds__(256)
k_proj(const bf16* __restrict__ o, const float* __restrict__ w2, float* __restrict__ h3) {
    int n = blockIdx.x * blockDim.x + threadIdx.x;
    if (n >= N_NODES) return;
    float a0 = 0.f, a1 = 0.f, a2 = 0.f;
    const bf16* row = o + (size_t)n * 64;
#pragma unroll
    for (int k8 = 0; k8 < 8; ++k8) {
        uint4 u = *(const uint4*)&row[k8 * 8];
        bf16* hv = (bf16*)&u;
#pragma unroll
        for (int j = 0; j < 8; ++j) {
            float av = __bfloat162float(hv[j]);
            int k = k8 * 8 + j;
            a0 = fmaf(av, w2[k * 3 + 0], a0);
            a1 = fmaf(av, w2[k * 3 + 1], a1);
            a2 = fmaf(av, w2[k * 3 + 2], a2);
        }
    }
    h3[n * 3 + 0] = a0;
    h3[n * 3 + 1] = a1;
    h3[n * 3 + 2] = a2;
}

// C=3 aggregation, thread-per-node, 4-deep MLP unroll
__global__ void __launch_bounds__(256)
k_agg3(const float* __restrict__ h, const int* __restrict__ cursor,
       const int2* __restrict__ csr, const float* __restrict__ dinv,
       const float* __restrict__ bias, float* __restrict__ y,
       float* __restrict__ bnsum) {
    int v = blockIdx.x * blockDim.x + threadIdx.x;
    float y0 = 0.f, y1 = 0.f, y2 = 0.f;
    bool valid = v < N_NODES;
    if (valid) {
        int end = cursor[v];
        int start = (v == 0) ? 0 : cursor[v - 1];
        float dv = dinv[v];
        float a0 = 0.f, a1 = 0.f, a2 = 0.f;
        int e = start;
        for (; e + 4 <= end; e += 4) {
            int2 c[4];
#pragma unroll
            for (int u = 0; u < 4; ++u) c[u] = csr[e + u];
#pragma unroll
            for (int u = 0; u < 4; ++u) {
                float w = __int_as_float(c[u].y);
                int s = c[u].x;
                a0 = fmaf(h[s * 3 + 0], w, a0);
                a1 = fmaf(h[s * 3 + 1], w, a1);
                a2 = fmaf(h[s * 3 + 2], w, a2);
            }
        }
        for (; e < end; ++e) {
            int2 c = csr[e];
            float w = __int_as_float(c.y);
            int s = c.x;
            a0 = fmaf(h[s * 3 + 0], w, a0);
            a1 = fmaf(h[s * 3 + 1], w, a1);
            a2 = fmaf(h[s * 3 + 2], w, a2);
        }
        float sl = 2.f * dv * dv;
        y0 = a0 * dv + sl * h[v * 3 + 0] + bias[0];
        y1 = a1 * dv + sl * h[v * 3 + 1] + bias[1];
        y2 = a2 * dv + sl * h[v * 3 + 2] + bias[2];
        y[v * 3 + 0] = y0;
        y[v * 3 + 1] = y1;
        y[v * 3 + 2] = y2;
    }
    __shared__ float sm[256];
    float vals[6] = {y0, y1, y2, y0 * y0, y1 * y1, y2 * y2};
    for (int c = 0; c < 6; ++c) {
        sm[threadIdx.x] = valid ? vals[c] : 0.f;
        __syncthreads();
        for (int off = 128; off > 0; off >>= 1) {
            if (threadIdx.x < off) sm[threadIdx.x] += sm[threadIdx.x + off];
            __syncthreads();
        }
        if (threadIdx.x == 0) atomicAdd(&bnsum[c], sm[0]);
        __syncthreads();
    }
}

// final stage post: BN(stats inline) + pool(3,1) + leaky + 3x3 linear + leaky
__global__ void k_post3(const float* __restrict__ y, const float* __restrict__ bnsum,
                        const float* __restrict__ g, const float* __restrict__ bb,
                        const float* __restrict__ lw, const float* __restrict__ lb,
                        float* __restrict__ out) {
    int v = blockIdx.x * blockDim.x + threadIdx.x;
    if (v >= N_NODES) return;
    float inv_n = 1.0f / (float)N_NODES;
    float sc[3], sh[3];
#pragma unroll
    for (int c = 0; c < 3; ++c) {
        float mean = bnsum[c] * inv_n;
        float var = fmaxf(bnsum[3 + c] * inv_n - mean * mean, 0.f);
        sc[c] = g[c] * rsqrtf(var + 1e-5f);
        sh[c] = bb[c] - mean * sc[c];
    }
    float z0 = fmaf(y[v * 3 + 0], sc[0], sh[0]);
    float z1 = fmaf(y[v * 3 + 1], sc[1], sh[1]);
    float z2 = fmaf(y[v * 3 + 2], sc[2], sh[2]);
    float p0 = fmaxf(z0, z1);
    float p1 = fmaxf(p0, z2);
    float p2 = fmaxf(z1, z2);
    float a0 = leaky(p0), a1 = leaky(p1), a2 = leaky(p2);
    float o0 = leaky(lb[0] + a0 * lw[0] + a1 * lw[1] + a2 * lw[2]);
    float o1 = leaky(lb[1] + a0 * lw[3] + a1 * lw[4] + a2 * lw[5]);
    float o2 = leaky(lb[2] + a0 * lw[6] + a1 * lw[7] + a2 * lw[8]);
    out[v * 3 + 0] = o0;
    out[v * 3 + 1] = o1;
    out[v * 3 + 2] = o2;
}

// ---------------- launcher ----------------

extern "C" void kernel_launch(void* const* d_in, const int* in_sizes, int n_in,
                              void* d_out, int out_size, void* d_ws, size_t ws_size,
                              hipStream_t stream) {
    const float* x  = (const float*)d_in[0];
    const int*   ei = (const int*)d_in[1];
    const float* w0 = (const float*)d_in[2];
    const float* b0 = (const float*)d_in[3];
    const float* g0 = (const float*)d_in[4];
    const float* bb0 = (const float*)d_in[5];
    const float* lw0 = (const float*)d_in[6];
    const float* lb0 = (const float*)d_in[7];
    const float* w1 = (const float*)d_in[8];
    const float* b1 = (const float*)d_in[9];
    const float* g1 = (const float*)d_in[10];
    const float* bb1 = (const float*)d_in[11];
    const float* lw1 = (const float*)d_in[12];
    const float* lb1 = (const float*)d_in[13];
    const float* w2 = (const float*)d_in[14];
    const float* b2 = (const float*)d_in[15];
    const float* g2 = (const float*)d_in[16];
    const float* bb2 = (const float*)d_in[17];
    const float* lw2 = (const float*)d_in[18];
    const float* lb2 = (const float*)d_in[19];
    float* out = (float*)d_out;

    // workspace layout (8B-aligned blocks first)
    char* w = (char*)d_ws;
    int2* csr = (int2*)w;          w += (size_t)N_EDGES * 8;     // 10.24 MB
    float* ybuf = (float*)w;       w += (size_t)N_NODES * 64 * 4; // 20.48 MB
    bf16* hb = (bf16*)w;           w += (size_t)N_NODES * 64 * 2; // 10.24 MB
    float* h3 = (float*)w;         w += (size_t)N_NODES * 3 * 4;  // 0.96 MB
    int* deg = (int*)w;            w += (size_t)N_NODES * 4;
    float* dinv = (float*)w;       w += (size_t)N_NODES * 4;
    int* cursor = (int*)w;         w += (size_t)N_NODES * 4;
    int* partial = (int*)w;        w += 512 * 4;
    float* bnsum = (float*)w;      w += 384 * 4;

    const int EB = (N_EDGES + 255) / 256;
    const int NB = (N_NODES + 255) / 256;  // 313

    // --- graph/CSR setup (shared by all 3 stages) ---
    k_zero<<<NB, 256, 0, stream>>>(deg, bnsum);
    k_deg<<<EB, 256, 0, stream>>>(ei, deg);
    k_scanA<<<NB, 256, 0, stream>>>(deg, partial, dinv);
    k_scanB<<<1, 512, 0, stream>>>(partial, NB);
    k_scanC<<<NB, 256, 0, stream>>>(deg, partial, cursor);
    k_scatter<<<EB, 256, 0, stream>>>(ei, dinv, cursor, csr);

    // --- stage 0 ---
    k_h0<<<(N_NODES * 64 + 255) / 256, 256, 0, stream>>>(x, w0, hb);
    k_agg64<<<2500, 256, 0, stream>>>(hb, cursor, csr, dinv, b0, ybuf, bnsum);
    k_post64<1, true><<<625, 128, 0, stream>>>(ybuf, bnsum, g0, bb0, lw0, lb0, w1, hb);

    // --- stage 1 ---
    k_agg64<<<2500, 256, 0, stream>>>(hb, cursor, csr, dinv, b1, ybuf, bnsum + 128);
    k_post64<2, false><<<625, 128, 0, stream>>>(ybuf, bnsum + 128, g1, bb1, lw1, lb1, nullptr, hb);
    k_proj<<<NB, 256, 0, stream>>>(hb, w2, h3);

    // --- stage 2 (C=3) ---
    k_agg3<<<NB, 256, 0, stream>>>(h3, cursor, csr, dinv, b2, ybuf, bnsum + 256);
    k_post3<<<NB, 256, 0, stream>>>(ybuf, bnsum + 256, g2, bb2, lw2, lb2, out);
}

// Round 4
// 527.205 us; speedup vs baseline: 1.6836x; 1.0582x over previous
//
#include <hip/hip_runtime.h>
#include <hip/hip_bf16.h>
#include <math.h>

#define N_NODES 80000
#define N_EDGES 1280000
#define CHUNK 128
#define N_CHUNKS (N_EDGES / CHUNK)  // 10000

typedef __hip_bfloat16 bf16;

__device__ __forceinline__ float leaky(float x) { return x >= 0.f ? x : 0.01f * x; }

// ---------------- setup kernels ----------------

__global__ void k_zero(int* deg, float* bnsums) {
    int i = blockIdx.x * blockDim.x + threadIdx.x;
    if (i < N_NODES) deg[i] = 0;
    if (i < 384) bnsums[i] = 0.f;
}

__global__ void k_deg(const int* __restrict__ ei, int* __restrict__ deg) {
    int e = blockIdx.x * blockDim.x + threadIdx.x;
    if (e < N_EDGES) {
        int dst = ei[N_EDGES + e];
        atomicAdd(&deg[dst], 1);
    }
}

__global__ void k_scanA(const int* __restrict__ deg, int* __restrict__ partial,
                        float* __restrict__ dinv) {
    __shared__ int s[256];
    int t = threadIdx.x;
    int i = blockIdx.x * 256 + t;
    int v = (i < N_NODES) ? deg[i] : 0;
    if (i < N_NODES) dinv[i] = rsqrtf((float)v + 2.0f);  // + self-loop weight 2
    s[t] = v;
    __syncthreads();
    for (int off = 128; off > 0; off >>= 1) {
        if (t < off) s[t] += s[t + off];
        __syncthreads();
    }
    if (t == 0) partial[blockIdx.x] = s[0];
}

__global__ void k_scanB(int* partial, int nb) {
    __shared__ int s[512];
    int t = threadIdx.x;
    int v = (t < nb) ? partial[t] : 0;
    s[t] = v;
    __syncthreads();
    for (int off = 1; off < 512; off <<= 1) {
        int x = (t >= off) ? s[t - off] : 0;
        __syncthreads();
        s[t] += x;
        __syncthreads();
    }
    if (t < nb) partial[t] = s[t] - v;  // exclusive
}

__global__ void k_scanC(const int* __restrict__ deg, const int* __restrict__ partial,
                        int* __restrict__ cursor) {
    __shared__ int s[256];
    int t = threadIdx.x;
    int i = blockIdx.x * 256 + t;
    int v = (i < N_NODES) ? deg[i] : 0;
    s[t] = v;
    __syncthreads();
    for (int off = 1; off < 256; off <<= 1) {
        int x = (t >= off) ? s[t - off] : 0;
        __syncthreads();
        s[t] += x;
        __syncthreads();
    }
    if (i < N_NODES) cursor[i] = partial[blockIdx.x] + s[t] - v;
}

// bucket edges by dst; record = {src, dinv[src]*dinv[dst], dst, 0}
__global__ void k_scatter(const int* __restrict__ ei, const float* __restrict__ dinv,
                          int* __restrict__ cursor, int4* __restrict__ ed) {
    int e = blockIdx.x * blockDim.x + threadIdx.x;
    if (e < N_EDGES) {
        int src = ei[e];
        int dst = ei[N_EDGES + e];
        float wf = dinv[src] * dinv[dst];
        int p = atomicAdd(&cursor[dst], 1);
        ed[p] = make_int4(src, __float_as_int(wf), dst, 0);
    }
}

// h0 = x @ W0 (bf16 out)
__global__ void k_h0(const float* __restrict__ x, const float* __restrict__ W0,
                     bf16* __restrict__ h) {
    int tid = blockIdx.x * blockDim.x + threadIdx.x;
    if (tid < N_NODES * 64) {
        int v = tid >> 6, c = tid & 63;
        float x0 = x[v * 3], x1 = x[v * 3 + 1], x2 = x[v * 3 + 2];
        h[tid] = __float2bfloat16(x0 * W0[c] + x1 * W0[64 + c] + x2 * W0[128 + c]);
    }
}

// ---------------- per-stage kernels ----------------

// y pre-init with self-loop + bias (atomics land on top of this)
__global__ void k_yinit(const bf16* __restrict__ hb, const float* __restrict__ dinv,
                        const float* __restrict__ bias, float* __restrict__ y) {
    int tid = blockIdx.x * blockDim.x + threadIdx.x;
    if (tid < N_NODES * 64) {
        int v = tid >> 6, c = tid & 63;
        float dv = dinv[v];
        y[tid] = 2.f * dv * dv * __bfloat162float(hb[tid]) + bias[c];
    }
}

// edge-stream segmented aggregation: wave = 128-edge strip, lane = channel.
// All iterations independent; segment flushes are fire-and-forget atomics.
__global__ void __launch_bounds__(256)
k_agg_es(const bf16* __restrict__ hb, const int4* __restrict__ ed,
         float* __restrict__ y) {
    int lane = threadIdx.x & 63;
    int wid = (blockIdx.x * blockDim.x + threadIdx.x) >> 6;
    if (wid >= N_CHUNKS) return;
    int e = wid * CHUNK;
    int4 c[8];
#pragma unroll
    for (int u = 0; u < 8; ++u) c[u] = ed[e + u];
    float acc = 0.f;
    int cur = __builtin_amdgcn_readfirstlane(c[0].z);
    for (int b = 0; b < CHUNK / 8; ++b) {
        // gathers for current batch (independent, issued up front)
        float pv[8];
#pragma unroll
        for (int u = 0; u < 8; ++u)
            pv[u] = __bfloat162float(hb[(size_t)c[u].x * 64 + lane]) * __int_as_float(c[u].y);
        // prefetch next batch records
        int4 cn[8];
        if (b < CHUNK / 8 - 1) {
            int en = e + 8;
#pragma unroll
            for (int u = 0; u < 8; ++u) cn[u] = ed[en + u];
        }
        // segmented accumulate (wave-uniform dst compares)
#pragma unroll
        for (int u = 0; u < 8; ++u) {
            int du = __builtin_amdgcn_readfirstlane(c[u].z);
            if (du != cur) {
                atomicAdd(&y[(size_t)cur * 64 + lane], acc);
                acc = 0.f;
                cur = du;
            }
            acc += pv[u];
        }
        e += 8;
        if (b < CHUNK / 8 - 1) {
#pragma unroll
            for (int u = 0; u < 8; ++u) c[u] = cn[u];
        }
    }
    atomicAdd(&y[(size_t)cur * 64 + lane], acc);
}

// per-channel sum / sumsq of final y
__global__ void __launch_bounds__(256)
k_bnstats(const float* __restrict__ y, float* __restrict__ bnsum) {
    int tid = blockIdx.x * blockDim.x + threadIdx.x;
    int stride = gridDim.x * blockDim.x;  // multiple of 64 -> lane == channel
    float bs = 0.f, bss = 0.f;
    for (size_t i = tid; i < (size_t)N_NODES * 64; i += stride) {
        float v = y[i];
        bs += v;
        bss += v * v;
    }
    __shared__ float s1[256], s2[256];
    s1[threadIdx.x] = bs;
    s2[threadIdx.x] = bss;
    __syncthreads();
    if (threadIdx.x < 64) {
        float t1 = s1[threadIdx.x] + s1[threadIdx.x + 64] + s1[threadIdx.x + 128] + s1[threadIdx.x + 192];
        float t2 = s2[threadIdx.x] + s2[threadIdx.x + 64] + s2[threadIdx.x + 128] + s2[threadIdx.x + 192];
        atomicAdd(&bnsum[threadIdx.x], t1);
        atomicAdd(&bnsum[64 + threadIdx.x], t2);
    }
}

// BN + maxpool + leaky + (a@lw.T+lb) + leaky [+ @Wn], register-tiled GEMM.
template <int P, bool MM2>
__global__ void __launch_bounds__(128)
k_post64(const float* __restrict__ y, const float* __restrict__ bnsum,
         const float* __restrict__ g, const float* __restrict__ bb,
         const float* __restrict__ lw, const float* __restrict__ lb,
         const float* __restrict__ Wn, bf16* __restrict__ hout) {
    __shared__ float s_aT[2][64 * 36];  // per-wave activation tile (transposed), reused as oT
    __shared__ float s_lwT[64 * 64];    // lw transposed: [k][c]
    __shared__ float s_Wn[MM2 ? 64 * 64 : 1];
    int t = threadIdx.x;
    int w = t >> 6, lane = t & 63;
    for (int k0 = t; k0 < 4096; k0 += 128) {
        int kk = k0 >> 6, cc = k0 & 63;
        s_lwT[kk * 64 + cc] = lw[cc * 64 + kk];
        if (MM2) s_Wn[k0] = Wn[k0];
    }
    float inv_n = 1.0f / (float)N_NODES;
    float mean = bnsum[lane] * inv_n;
    float var = fmaxf(bnsum[64 + lane] * inv_n - mean * mean, 0.f);
    float sc = g[lane] * rsqrtf(var + 1e-5f);
    float sh = bb[lane] - mean * sc;
    int c0 = (lane >> 3) * 8, n0 = (lane & 7) * 4;
    float lbv[8];
#pragma unroll
    for (int i = 0; i < 8; ++i) lbv[i] = lb[c0 + i];
    float* aT = s_aT[w];

    for (int tile = blockIdx.x; tile < N_NODES / 64; tile += gridDim.x) {
        int nbase = tile * 64 + w * 32;
        __syncthreads();
#pragma unroll 4
        for (int i = 0; i < 32; ++i) {
            float z = fmaf(y[(size_t)(nbase + i) * 64 + lane], sc, sh);
            float m = z;
#pragma unroll
            for (int d = 1; d <= P; ++d) {
                float up = __shfl(z, lane + d);
                float dn = __shfl(z, lane - d);
                m = fmaxf(m, (lane + d < 64) ? up : -INFINITY);
                m = fmaxf(m, (lane - d >= 0) ? dn : -INFINITY);
            }
            aT[lane * 36 + i] = leaky(m);
        }
        __syncthreads();
        float acc[4][8];
#pragma unroll
        for (int nn = 0; nn < 4; ++nn)
#pragma unroll
            for (int i = 0; i < 8; ++i) acc[nn][i] = lbv[i];
#pragma unroll 8
        for (int k = 0; k < 64; ++k) {
            float4 av = *(const float4*)&aT[k * 36 + n0];
            float4 w0 = *(const float4*)&s_lwT[k * 64 + c0];
            float4 w1 = *(const float4*)&s_lwT[k * 64 + c0 + 4];
            float a4[4] = {av.x, av.y, av.z, av.w};
            float wv[8] = {w0.x, w0.y, w0.z, w0.w, w1.x, w1.y, w1.z, w1.w};
#pragma unroll
            for (int nn = 0; nn < 4; ++nn)
#pragma unroll
                for (int i = 0; i < 8; ++i) acc[nn][i] = fmaf(a4[nn], wv[i], acc[nn][i]);
        }
#pragma unroll
        for (int nn = 0; nn < 4; ++nn)
#pragma unroll
            for (int i = 0; i < 8; ++i) acc[nn][i] = leaky(acc[nn][i]);

        if (MM2) {
#pragma unroll
            for (int i = 0; i < 8; ++i) {
                float4 ov = make_float4(acc[0][i], acc[1][i], acc[2][i], acc[3][i]);
                *(float4*)&aT[(c0 + i) * 36 + n0] = ov;
            }
            float acc2[4][8];
#pragma unroll
            for (int nn = 0; nn < 4; ++nn)
#pragma unroll
                for (int i = 0; i < 8; ++i) acc2[nn][i] = 0.f;
#pragma unroll 8
            for (int k = 0; k < 64; ++k) {
                float4 av = *(const float4*)&aT[k * 36 + n0];
                float4 w0 = *(const float4*)&s_Wn[k * 64 + c0];
                float4 w1 = *(const float4*)&s_Wn[k * 64 + c0 + 4];
                float a4[4] = {av.x, av.y, av.z, av.w};
                float wv[8] = {w0.x, w0.y, w0.z, w0.w, w1.x, w1.y, w1.z, w1.w};
#pragma unroll
                for (int nn = 0; nn < 4; ++nn)
#pragma unroll
                    for (int i = 0; i < 8; ++i) acc2[nn][i] = fmaf(a4[nn], wv[i], acc2[nn][i]);
            }
#pragma unroll
            for (int nn = 0; nn < 4; ++nn) {
                bf16 pk[8];
#pragma unroll
                for (int i = 0; i < 8; ++i) pk[i] = __float2bfloat16(acc2[nn][i]);
                *(uint4*)&hout[(size_t)(nbase + n0 + nn) * 64 + c0] = *(uint4*)pk;
            }
        } else {
#pragma unroll
            for (int nn = 0; nn < 4; ++nn) {
                bf16 pk[8];
#pragma unroll
                for (int i = 0; i < 8; ++i) pk[i] = __float2bfloat16(acc[nn][i]);
                *(uint4*)&hout[(size_t)(nbase + n0 + nn) * 64 + c0] = *(uint4*)pk;
            }
        }
    }
}

// h3 = o(bf16) @ w2 [64,3] -> fp32 [N,3]
__global__ void __launch_bounds__(256)
k_proj(const bf16* __restrict__ o, const float* __restrict__ w2, float* __restrict__ h3) {
    int n = blockIdx.x * blockDim.x + threadIdx.x;
    if (n >= N_NODES) return;
    float a0 = 0.f, a1 = 0.f, a2 = 0.f;
    const bf16* row = o + (size_t)n * 64;
#pragma unroll
    for (int k8 = 0; k8 < 8; ++k8) {
        uint4 u = *(const uint4*)&row[k8 * 8];
        bf16* hv = (bf16*)&u;
#pragma unroll
        for (int j = 0; j < 8; ++j) {
            float av = __bfloat162float(hv[j]);
            int k = k8 * 8 + j;
            a0 = fmaf(av, w2[k * 3 + 0], a0);
            a1 = fmaf(av, w2[k * 3 + 1], a1);
            a2 = fmaf(av, w2[k * 3 + 2], a2);
        }
    }
    h3[n * 3 + 0] = a0;
    h3[n * 3 + 1] = a1;
    h3[n * 3 + 2] = a2;
}

// C=3 aggregation, thread-per-node (w already = dinv[s]*dinv[d])
__global__ void __launch_bounds__(256)
k_agg3(const float* __restrict__ h, const int* __restrict__ cursor,
       const int4* __restrict__ ed, const float* __restrict__ dinv,
       const float* __restrict__ bias, float* __restrict__ y,
       float* __restrict__ bnsum) {
    int v = blockIdx.x * blockDim.x + threadIdx.x;
    float y0 = 0.f, y1 = 0.f, y2 = 0.f;
    bool valid = v < N_NODES;
    if (valid) {
        int end = cursor[v];
        int start = (v == 0) ? 0 : cursor[v - 1];
        float dv = dinv[v];
        float a0 = 0.f, a1 = 0.f, a2 = 0.f;
        int e = start;
        for (; e + 4 <= end; e += 4) {
            int4 c[4];
#pragma unroll
            for (int u = 0; u < 4; ++u) c[u] = ed[e + u];
#pragma unroll
            for (int u = 0; u < 4; ++u) {
                float w = __int_as_float(c[u].y);
                int s = c[u].x;
                a0 = fmaf(h[s * 3 + 0], w, a0);
                a1 = fmaf(h[s * 3 + 1], w, a1);
                a2 = fmaf(h[s * 3 + 2], w, a2);
            }
        }
        for (; e < end; ++e) {
            int4 c = ed[e];
            float w = __int_as_float(c.y);
            int s = c.x;
            a0 = fmaf(h[s * 3 + 0], w, a0);
            a1 = fmaf(h[s * 3 + 1], w, a1);
            a2 = fmaf(h[s * 3 + 2], w, a2);
        }
        float sl = 2.f * dv * dv;
        y0 = a0 + sl * h[v * 3 + 0] + bias[0];
        y1 = a1 + sl * h[v * 3 + 1] + bias[1];
        y2 = a2 + sl * h[v * 3 + 2] + bias[2];
        y[v * 3 + 0] = y0;
        y[v * 3 + 1] = y1;
        y[v * 3 + 2] = y2;
    }
    __shared__ float sm[256];
    float vals[6] = {y0, y1, y2, y0 * y0, y1 * y1, y2 * y2};
    for (int c = 0; c < 6; ++c) {
        sm[threadIdx.x] = valid ? vals[c] : 0.f;
        __syncthreads();
        for (int off = 128; off > 0; off >>= 1) {
            if (threadIdx.x < off) sm[threadIdx.x] += sm[threadIdx.x + off];
            __syncthreads();
        }
        if (threadIdx.x == 0) atomicAdd(&bnsum[c], sm[0]);
        __syncthreads();
    }
}

// final stage post: BN(stats inline) + pool(3,1) + leaky + 3x3 linear + leaky
__global__ void k_post3(const float* __restrict__ y, const float* __restrict__ bnsum,
                        const float* __restrict__ g, const float* __restrict__ bb,
                        const float* __restrict__ lw, const float* __restrict__ lb,
                        float* __restrict__ out) {
    int v = blockIdx.x * blockDim.x + threadIdx.x;
    if (v >= N_NODES) return;
    float inv_n = 1.0f / (float)N_NODES;
    float sc[3], sh[3];
#pragma unroll
    for (int c = 0; c < 3; ++c) {
        float mean = bnsum[c] * inv_n;
        float var = fmaxf(bnsum[3 + c] * inv_n - mean * mean, 0.f);
        sc[c] = g[c] * rsqrtf(var + 1e-5f);
        sh[c] = bb[c] - mean * sc[c];
    }
    float z0 = fmaf(y[v * 3 + 0], sc[0], sh[0]);
    float z1 = fmaf(y[v * 3 + 1], sc[1], sh[1]);
    float z2 = fmaf(y[v * 3 + 2], sc[2], sh[2]);
    float p0 = fmaxf(z0, z1);
    float p1 = fmaxf(p0, z2);
    float p2 = fmaxf(z1, z2);
    float a0 = leaky(p0), a1 = leaky(p1), a2 = leaky(p2);
    float o0 = leaky(lb[0] + a0 * lw[0] + a1 * lw[1] + a2 * lw[2]);
    float o1 = leaky(lb[1] + a0 * lw[3] + a1 * lw[4] + a2 * lw[5]);
    float o2 = leaky(lb[2] + a0 * lw[6] + a1 * lw[7] + a2 * lw[8]);
    out[v * 3 + 0] = o0;
    out[v * 3 + 1] = o1;
    out[v * 3 + 2] = o2;
}

// ---------------- launcher ----------------

extern "C" void kernel_launch(void* const* d_in, const int* in_sizes, int n_in,
                              void* d_out, int out_size, void* d_ws, size_t ws_size,
                              hipStream_t stream) {
    const float* x  = (const float*)d_in[0];
    const int*   ei = (const int*)d_in[1];
    const float* w0 = (const float*)d_in[2];
    const float* b0 = (const float*)d_in[3];
    const float* g0 = (const float*)d_in[4];
    const float* bb0 = (const float*)d_in[5];
    const float* lw0 = (const float*)d_in[6];
    const float* lb0 = (const float*)d_in[7];
    const float* w1 = (const float*)d_in[8];
    const float* b1 = (const float*)d_in[9];
    const float* g1 = (const float*)d_in[10];
    const float* bb1 = (const float*)d_in[11];
    const float* lw1 = (const float*)d_in[12];
    const float* lb1 = (const float*)d_in[13];
    const float* w2 = (const float*)d_in[14];
    const float* b2 = (const float*)d_in[15];
    const float* g2 = (const float*)d_in[16];
    const float* bb2 = (const float*)d_in[17];
    const float* lw2 = (const float*)d_in[18];
    const float* lb2 = (const float*)d_in[19];
    float* out = (float*)d_out;

    // workspace layout (16B-aligned first)
    char* w = (char*)d_ws;
    int4* ed = (int4*)w;           w += (size_t)N_EDGES * 16;     // 20.48 MB
    float* ybuf = (float*)w;       w += (size_t)N_NODES * 64 * 4; // 20.48 MB
    bf16* hb = (bf16*)w;           w += (size_t)N_NODES * 64 * 2; // 10.24 MB
    int* deg = (int*)w;            w += (size_t)N_NODES * 4;
    float* dinv = (float*)w;       w += (size_t)N_NODES * 4;
    int* cursor = (int*)w;         w += (size_t)N_NODES * 4;
    int* partial = (int*)w;        w += 512 * 4;
    float* bnsum = (float*)w;      w += 384 * 4;
    // h3 overlays the upper half of ybuf (stage-2 y3 uses the bottom 0.96 MB)
    float* h3 = ybuf + (size_t)N_NODES * 32;

    const int EB = (N_EDGES + 255) / 256;
    const int NB = (N_NODES + 255) / 256;  // 313

    // --- graph/CSR setup (shared by all 3 stages) ---
    k_zero<<<NB, 256, 0, stream>>>(deg, bnsum);
    k_deg<<<EB, 256, 0, stream>>>(ei, deg);
    k_scanA<<<NB, 256, 0, stream>>>(deg, partial, dinv);
    k_scanB<<<1, 512, 0, stream>>>(partial, NB);
    k_scanC<<<NB, 256, 0, stream>>>(deg, partial, cursor);
    k_scatter<<<EB, 256, 0, stream>>>(ei, dinv, cursor, ed);

    // --- stage 0 ---
    k_h0<<<(N_NODES * 64 + 255) / 256, 256, 0, stream>>>(x, w0, hb);
    k_yinit<<<(N_NODES * 64 + 255) / 256, 256, 0, stream>>>(hb, dinv, b0, ybuf);
    k_agg_es<<<2500, 256, 0, stream>>>(hb, ed, ybuf);
    k_bnstats<<<640, 256, 0, stream>>>(ybuf, bnsum);
    k_post64<1, true><<<1250, 128, 0, stream>>>(ybuf, bnsum, g0, bb0, lw0, lb0, w1, hb);

    // --- stage 1 ---
    k_yinit<<<(N_NODES * 64 + 255) / 256, 256, 0, stream>>>(hb, dinv, b1, ybuf);
    k_agg_es<<<2500, 256, 0, stream>>>(hb, ed, ybuf);
    k_bnstats<<<640, 256, 0, stream>>>(ybuf, bnsum + 128);
    k_post64<2, false><<<1250, 128, 0, stream>>>(ybuf, bnsum + 128, g1, bb1, lw1, lb1, nullptr, hb);
    k_proj<<<NB, 256, 0, stream>>>(hb, w2, h3);

    // --- stage 2 (C=3) ---
    k_agg3<<<NB, 256, 0, stream>>>(h3, cursor, ed, dinv, b2, ybuf, bnsum + 256);
    k_post3<<<NB, 256, 0, stream>>>(ybuf, bnsum + 256, g2, bb2, lw2, lb2, out);
}

// Round 6
// 507.949 us; speedup vs baseline: 1.7474x; 1.0379x over previous
//
#include <hip/hip_runtime.h>
#include <hip/hip_bf16.h>
#include <math.h>

#define N_NODES 80000
#define N_EDGES 1280000
#define CHUNK 128
#define N_CHUNKS (N_EDGES / CHUNK)  // 10000
#define NBKT 8
#define BKT_DIV 10000               // bucket = dst / 10000  -> 0..7
#define BKT_CAP 165000              // mean 160000, sigma ~374; huge margin
#define EPB 1280                    // edges per k_part block (grid 1000)

typedef __hip_bfloat16 bf16;

__device__ __forceinline__ float leaky(float x) { return x >= 0.f ? x : 0.01f * x; }

// ---------------- setup kernels ----------------

__global__ void k_zero(int* deg, float* bnsums, int* tails) {
    int i = blockIdx.x * blockDim.x + threadIdx.x;
    if (i < N_NODES) deg[i] = 0;
    if (i < 384) bnsums[i] = 0.f;
    if (i < NBKT) tails[i] = 0;
}

// pass 1: bin (src,dst) pairs by dst-range with coalesced writes; fold deg count.
__global__ void __launch_bounds__(256)
k_part(const int* __restrict__ ei, int2* __restrict__ pairs,
       int* __restrict__ tails, int* __restrict__ deg) {
    __shared__ int cnt[NBKT], off[NBKT];
    int t = threadIdx.x;
    if (t < NBKT) cnt[t] = 0;
    __syncthreads();
    int base = blockIdx.x * EPB;
    int2 loc[5];
#pragma unroll
    for (int u = 0; u < 5; ++u) {
        int e = base + u * 256 + t;
        int s = ei[e], d = ei[N_EDGES + e];
        loc[u] = make_int2(s, d);
        atomicAdd(&cnt[d / BKT_DIV], 1);
        atomicAdd(&deg[d], 1);
    }
    __syncthreads();
    if (t < NBKT) off[t] = atomicAdd(&tails[t], cnt[t]);
    __syncthreads();
#pragma unroll
    for (int u = 0; u < 5; ++u) {
        int b = loc[u].y / BKT_DIV;
        int pos = atomicAdd(&off[b], 1);
        pairs[(size_t)b * BKT_CAP + pos] = loc[u];
    }
}

__global__ void k_scanA(const int* __restrict__ deg, int* __restrict__ partial,
                        float* __restrict__ dinv) {
    __shared__ int s[256];
    int t = threadIdx.x;
    int i = blockIdx.x * 256 + t;
    int v = (i < N_NODES) ? deg[i] : 0;
    if (i < N_NODES) dinv[i] = rsqrtf((float)v + 2.0f);  // + self-loop weight 2
    s[t] = v;
    __syncthreads();
    for (int off = 128; off > 0; off >>= 1) {
        if (t < off) s[t] += s[t + off];
        __syncthreads();
    }
    if (t == 0) partial[blockIdx.x] = s[0];
}

__global__ void k_scanB(int* partial, int nb) {
    __shared__ int s[512];
    int t = threadIdx.x;
    int v = (t < nb) ? partial[t] : 0;
    s[t] = v;
    __syncthreads();
    for (int off = 1; off < 512; off <<= 1) {
        int x = (t >= off) ? s[t - off] : 0;
        __syncthreads();
        s[t] += x;
        __syncthreads();
    }
    if (t < nb) partial[t] = s[t] - v;  // exclusive
}

__global__ void k_scanC(const int* __restrict__ deg, const int* __restrict__ partial,
                        int* __restrict__ cursor) {
    __shared__ int s[256];
    int t = threadIdx.x;
    int i = blockIdx.x * 256 + t;
    int v = (i < N_NODES) ? deg[i] : 0;
    s[t] = v;
    __syncthreads();
    for (int off = 1; off < 256; off <<= 1) {
        int x = (t >= off) ? s[t - off] : 0;
        __syncthreads();
        s[t] += x;
        __syncthreads();
    }
    if (i < N_NODES) cursor[i] = partial[blockIdx.x] + s[t] - v;
}

// pass 2: per-bucket CSR scatter. blockIdx&7 == bucket matches the XCD
// round-robin heuristic, so each XCD's writes stay in a ~2.6 MB slice.
__global__ void __launch_bounds__(256)
k_scatter2(const int2* __restrict__ pairs, const int* __restrict__ tails,
           const float* __restrict__ dinv, int* __restrict__ cursor,
           int4* __restrict__ ed) {
    int bucket = blockIdx.x & 7;
    int jb = blockIdx.x >> 3;
    int nb = gridDim.x >> 3;
    int cnt = tails[bucket];
    const int2* lst = pairs + (size_t)bucket * BKT_CAP;
    for (int i = jb * 256 + threadIdx.x; i < cnt; i += nb * 256) {
        int2 pr = lst[i];
        float wf = dinv[pr.x] * dinv[pr.y];
        int p = atomicAdd(&cursor[pr.y], 1);
        ed[p] = make_int4(pr.x, __float_as_int(wf), pr.y, 0);
    }
}

// h0 = x @ W0 (bf16) fused with stage-0 y-init: y0 = 2*dinv^2*h0 + b0
__global__ void k_h0y(const float* __restrict__ x, const float* __restrict__ W0,
                      const float* __restrict__ dinv, const float* __restrict__ bias,
                      bf16* __restrict__ h, float* __restrict__ y) {
    int tid = blockIdx.x * blockDim.x + threadIdx.x;
    if (tid < N_NODES * 64) {
        int v = tid >> 6, c = tid & 63;
        float x0 = x[v * 3], x1 = x[v * 3 + 1], x2 = x[v * 3 + 2];
        bf16 hb = __float2bfloat16(x0 * W0[c] + x1 * W0[64 + c] + x2 * W0[128 + c]);
        h[tid] = hb;
        float dv = dinv[v];
        y[tid] = 2.f * dv * dv * __bfloat162float(hb) + bias[c];
    }
}

// ---------------- per-stage kernels ----------------

// y pre-init with self-loop + bias (stage 1)
__global__ void k_yinit(const bf16* __restrict__ hb, const float* __restrict__ dinv,
                        const float* __restrict__ bias, float* __restrict__ y) {
    int tid = blockIdx.x * blockDim.x + threadIdx.x;
    if (tid < N_NODES * 64) {
        int v = tid >> 6, c = tid & 63;
        float dv = dinv[v];
        y[tid] = 2.f * dv * dv * __bfloat162float(hb[tid]) + bias[c];
    }
}

// edge-stream segmented aggregation: wave = 128-edge strip, lane = channel.
__global__ void __launch_bounds__(256)
k_agg_es(const bf16* __restrict__ hb, const int4* __restrict__ ed,
         float* __restrict__ y) {
    int lane = threadIdx.x & 63;
    int wid = (blockIdx.x * blockDim.x + threadIdx.x) >> 6;
    if (wid >= N_CHUNKS) return;
    int e = wid * CHUNK;
    int4 c[8];
#pragma unroll
    for (int u = 0; u < 8; ++u) c[u] = ed[e + u];
    float acc = 0.f;
    int cur = __builtin_amdgcn_readfirstlane(c[0].z);
    for (int b = 0; b < CHUNK / 8; ++b) {
        float pv[8];
#pragma unroll
        for (int u = 0; u < 8; ++u)
            pv[u] = __bfloat162float(hb[(size_t)c[u].x * 64 + lane]) * __int_as_float(c[u].y);
        int4 cn[8];
        if (b < CHUNK / 8 - 1) {
            int en = e + 8;
#pragma unroll
            for (int u = 0; u < 8; ++u) cn[u] = ed[en + u];
        }
#pragma unroll
        for (int u = 0; u < 8; ++u) {
            int du = __builtin_amdgcn_readfirstlane(c[u].z);
            if (du != cur) {
                atomicAdd(&y[(size_t)cur * 64 + lane], acc);
                acc = 0.f;
                cur = du;
            }
            acc += pv[u];
        }
        e += 8;
        if (b < CHUNK / 8 - 1) {
#pragma unroll
            for (int u = 0; u < 8; ++u) c[u] = cn[u];
        }
    }
    atomicAdd(&y[(size_t)cur * 64 + lane], acc);
}

// per-channel sum / sumsq of final y
__global__ void __launch_bounds__(256)
k_bnstats(const float* __restrict__ y, float* __restrict__ bnsum) {
    int tid = blockIdx.x * blockDim.x + threadIdx.x;
    int stride = gridDim.x * blockDim.x;
    float bs = 0.f, bss = 0.f;
    for (size_t i = tid; i < (size_t)N_NODES * 64; i += stride) {
        float v = y[i];
        bs += v;
        bss += v * v;
    }
    __shared__ float s1[256], s2[256];
    s1[threadIdx.x] = bs;
    s2[threadIdx.x] = bss;
    __syncthreads();
    if (threadIdx.x < 64) {
        float t1 = s1[threadIdx.x] + s1[threadIdx.x + 64] + s1[threadIdx.x + 128] + s1[threadIdx.x + 192];
        float t2 = s2[threadIdx.x] + s2[threadIdx.x + 64] + s2[threadIdx.x + 128] + s2[threadIdx.x + 192];
        atomicAdd(&bnsum[threadIdx.x], t1);
        atomicAdd(&bnsum[64 + threadIdx.x], t2);
    }
}

// BN + maxpool + leaky + (a@lw.T+lb) + leaky + second matmul, register-tiled.
// MODE 0: phase3 = o @ Wn (64x64) -> bf16 hout.
// MODE 1: phase3 = o @ Wn (64x3)  -> fp32 out3 (proj fused, hout unused).
template <int P, int MODE>
__global__ void __launch_bounds__(128)
k_post64(const float* __restrict__ y, const float* __restrict__ bnsum,
         const float* __restrict__ g, const float* __restrict__ bb,
         const float* __restrict__ lw, const float* __restrict__ lb,
         const float* __restrict__ Wn, bf16* __restrict__ hout,
         float* __restrict__ out3) {
    __shared__ float s_aT[2][64 * 36];  // per-wave activation tile (transposed), reused as oT
    __shared__ float s_lwT[64 * 64];    // lw transposed: [k][c]
    __shared__ float s_Wn[MODE == 0 ? 64 * 64 : 64 * 3];
    int t = threadIdx.x;
    int w = t >> 6, lane = t & 63;
    for (int k0 = t; k0 < 4096; k0 += 128) {
        int kk = k0 >> 6, cc = k0 & 63;
        s_lwT[kk * 64 + cc] = lw[cc * 64 + kk];
        if (MODE == 0) s_Wn[k0] = Wn[k0];
    }
    if (MODE == 1) {
        // strided: 192 elements, 128 threads (R5 bug: single-shot load missed 128..191)
        for (int i = t; i < 64 * 3; i += 128) s_Wn[i] = Wn[i];
    }
    float inv_n = 1.0f / (float)N_NODES;
    float mean = bnsum[lane] * inv_n;
    float var = fmaxf(bnsum[64 + lane] * inv_n - mean * mean, 0.f);
    float sc = g[lane] * rsqrtf(var + 1e-5f);
    float sh = bb[lane] - mean * sc;
    int c0 = (lane >> 3) * 8, n0 = (lane & 7) * 4;
    float lbv[8];
#pragma unroll
    for (int i = 0; i < 8; ++i) lbv[i] = lb[c0 + i];
    float* aT = s_aT[w];

    for (int tile = blockIdx.x; tile < N_NODES / 64; tile += gridDim.x) {
        int nbase = tile * 64 + w * 32;
        __syncthreads();  // also covers initial weight-fill -> first use
#pragma unroll 4
        for (int i = 0; i < 32; ++i) {
            float z = fmaf(y[(size_t)(nbase + i) * 64 + lane], sc, sh);
            float m = z;
#pragma unroll
            for (int d = 1; d <= P; ++d) {
                float up = __shfl(z, lane + d);
                float dn = __shfl(z, lane - d);
                m = fmaxf(m, (lane + d < 64) ? up : -INFINITY);
                m = fmaxf(m, (lane - d >= 0) ? dn : -INFINITY);
            }
            aT[lane * 36 + i] = leaky(m);
        }
        __syncthreads();
        // phase 2: o = leaky(a @ lw.T + lb)
        float acc[4][8];
#pragma unroll
        for (int nn = 0; nn < 4; ++nn)
#pragma unroll
            for (int i = 0; i < 8; ++i) acc[nn][i] = lbv[i];
#pragma unroll 8
        for (int k = 0; k < 64; ++k) {
            float4 av = *(const float4*)&aT[k * 36 + n0];
            float4 w0 = *(const float4*)&s_lwT[k * 64 + c0];
            float4 w1 = *(const float4*)&s_lwT[k * 64 + c0 + 4];
            float a4[4] = {av.x, av.y, av.z, av.w};
            float wv[8] = {w0.x, w0.y, w0.z, w0.w, w1.x, w1.y, w1.z, w1.w};
#pragma unroll
            for (int nn = 0; nn < 4; ++nn)
#pragma unroll
                for (int i = 0; i < 8; ++i) acc[nn][i] = fmaf(a4[nn], wv[i], acc[nn][i]);
        }
#pragma unroll
        for (int nn = 0; nn < 4; ++nn)
#pragma unroll
            for (int i = 0; i < 8; ++i) acc[nn][i] = leaky(acc[nn][i]);

        // write oT (aliases aT; same-wave LDS program order is safe)
#pragma unroll
        for (int i = 0; i < 8; ++i) {
            float4 ov = make_float4(acc[0][i], acc[1][i], acc[2][i], acc[3][i]);
            *(float4*)&aT[(c0 + i) * 36 + n0] = ov;
        }
        if (MODE == 0) {
            float acc2[4][8];
#pragma unroll
            for (int nn = 0; nn < 4; ++nn)
#pragma unroll
                for (int i = 0; i < 8; ++i) acc2[nn][i] = 0.f;
#pragma unroll 8
            for (int k = 0; k < 64; ++k) {
                float4 av = *(const float4*)&aT[k * 36 + n0];
                float4 w0 = *(const float4*)&s_Wn[k * 64 + c0];
                float4 w1 = *(const float4*)&s_Wn[k * 64 + c0 + 4];
                float a4[4] = {av.x, av.y, av.z, av.w};
                float wv[8] = {w0.x, w0.y, w0.z, w0.w, w1.x, w1.y, w1.z, w1.w};
#pragma unroll
                for (int nn = 0; nn < 4; ++nn)
#pragma unroll
                    for (int i = 0; i < 8; ++i) acc2[nn][i] = fmaf(a4[nn], wv[i], acc2[nn][i]);
            }
#pragma unroll
            for (int nn = 0; nn < 4; ++nn) {
                bf16 pk[8];
#pragma unroll
                for (int i = 0; i < 8; ++i) pk[i] = __float2bfloat16(acc2[nn][i]);
                *(uint4*)&hout[(size_t)(nbase + n0 + nn) * 64 + c0] = *(uint4*)pk;
            }
        } else {
            // proj fused: h3 = o @ w2 (64x3); 8 lanes duplicate, c0==0 writes
            float acc3[4][3];
#pragma unroll
            for (int nn = 0; nn < 4; ++nn)
#pragma unroll
                for (int j = 0; j < 3; ++j) acc3[nn][j] = 0.f;
#pragma unroll 8
            for (int k = 0; k < 64; ++k) {
                float4 av = *(const float4*)&aT[k * 36 + n0];
                float a4[4] = {av.x, av.y, av.z, av.w};
                float w0 = s_Wn[k * 3 + 0], w1 = s_Wn[k * 3 + 1], w2v = s_Wn[k * 3 + 2];
#pragma unroll
                for (int nn = 0; nn < 4; ++nn) {
                    acc3[nn][0] = fmaf(a4[nn], w0, acc3[nn][0]);
                    acc3[nn][1] = fmaf(a4[nn], w1, acc3[nn][1]);
                    acc3[nn][2] = fmaf(a4[nn], w2v, acc3[nn][2]);
                }
            }
            if (c0 == 0) {
#pragma unroll
                for (int nn = 0; nn < 4; ++nn) {
                    int node = nbase + n0 + nn;
                    out3[node * 3 + 0] = acc3[nn][0];
                    out3[node * 3 + 1] = acc3[nn][1];
                    out3[node * 3 + 2] = acc3[nn][2];
                }
            }
        }
    }
}

// C=3 aggregation, thread-per-node (w already = dinv[s]*dinv[d])
__global__ void __launch_bounds__(256)
k_agg3(const float* __restrict__ h, const int* __restrict__ cursor,
       const int4* __restrict__ ed, const float* __restrict__ dinv,
       const float* __restrict__ bias, float* __restrict__ y,
       float* __restrict__ bnsum) {
    int v = blockIdx.x * blockDim.x + threadIdx.x;
    float y0 = 0.f, y1 = 0.f, y2 = 0.f;
    bool valid = v < N_NODES;
    if (valid) {
        int end = cursor[v];
        int start = (v == 0) ? 0 : cursor[v - 1];
        float dv = dinv[v];
        float a0 = 0.f, a1 = 0.f, a2 = 0.f;
        int e = start;
        for (; e + 4 <= end; e += 4) {
            int4 c[4];
#pragma unroll
            for (int u = 0; u < 4; ++u) c[u] = ed[e + u];
#pragma unroll
            for (int u = 0; u < 4; ++u) {
                float w = __int_as_float(c[u].y);
                int s = c[u].x;
                a0 = fmaf(h[s * 3 + 0], w, a0);
                a1 = fmaf(h[s * 3 + 1], w, a1);
                a2 = fmaf(h[s * 3 + 2], w, a2);
            }
        }
        for (; e < end; ++e) {
            int4 c = ed[e];
            float w = __int_as_float(c.y);
            int s = c.x;
            a0 = fmaf(h[s * 3 + 0], w, a0);
            a1 = fmaf(h[s * 3 + 1], w, a1);
            a2 = fmaf(h[s * 3 + 2], w, a2);
        }
        float sl = 2.f * dv * dv;
        y0 = a0 + sl * h[v * 3 + 0] + bias[0];
        y1 = a1 + sl * h[v * 3 + 1] + bias[1];
        y2 = a2 + sl * h[v * 3 + 2] + bias[2];
        y[v * 3 + 0] = y0;
        y[v * 3 + 1] = y1;
        y[v * 3 + 2] = y2;
    }
    __shared__ float sm[256];
    float vals[6] = {y0, y1, y2, y0 * y0, y1 * y1, y2 * y2};
    for (int c = 0; c < 6; ++c) {
        sm[threadIdx.x] = valid ? vals[c] : 0.f;
        __syncthreads();
        for (int off = 128; off > 0; off >>= 1) {
            if (threadIdx.x < off) sm[threadIdx.x] += sm[threadIdx.x + off];
            __syncthreads();
        }
        if (threadIdx.x == 0) atomicAdd(&bnsum[c], sm[0]);
        __syncthreads();
    }
}

// final stage post: BN(stats inline) + pool(3,1) + leaky + 3x3 linear + leaky
__global__ void k_post3(const float* __restrict__ y, const float* __restrict__ bnsum,
                        const float* __restrict__ g, const float* __restrict__ bb,
                        const float* __restrict__ lw, const float* __restrict__ lb,
                        float* __restrict__ out) {
    int v = blockIdx.x * blockDim.x + threadIdx.x;
    if (v >= N_NODES) return;
    float inv_n = 1.0f / (float)N_NODES;
    float sc[3], sh[3];
#pragma unroll
    for (int c = 0; c < 3; ++c) {
        float mean = bnsum[c] * inv_n;
        float var = fmaxf(bnsum[3 + c] * inv_n - mean * mean, 0.f);
        sc[c] = g[c] * rsqrtf(var + 1e-5f);
        sh[c] = bb[c] - mean * sc[c];
    }
    float z0 = fmaf(y[v * 3 + 0], sc[0], sh[0]);
    float z1 = fmaf(y[v * 3 + 1], sc[1], sh[1]);
    float z2 = fmaf(y[v * 3 + 2], sc[2], sh[2]);
    float p0 = fmaxf(z0, z1);
    float p1 = fmaxf(p0, z2);
    float p2 = fmaxf(z1, z2);
    float a0 = leaky(p0), a1 = leaky(p1), a2 = leaky(p2);
    float o0 = leaky(lb[0] + a0 * lw[0] + a1 * lw[1] + a2 * lw[2]);
    float o1 = leaky(lb[1] + a0 * lw[3] + a1 * lw[4] + a2 * lw[5]);
    float o2 = leaky(lb[2] + a0 * lw[6] + a1 * lw[7] + a2 * lw[8]);
    out[v * 3 + 0] = o0;
    out[v * 3 + 1] = o1;
    out[v * 3 + 2] = o2;
}

// ---------------- launcher ----------------

extern "C" void kernel_launch(void* const* d_in, const int* in_sizes, int n_in,
                              void* d_out, int out_size, void* d_ws, size_t ws_size,
                              hipStream_t stream) {
    const float* x  = (const float*)d_in[0];
    const int*   ei = (const int*)d_in[1];
    const float* w0 = (const float*)d_in[2];
    const float* b0 = (const float*)d_in[3];
    const float* g0 = (const float*)d_in[4];
    const float* bb0 = (const float*)d_in[5];
    const float* lw0 = (const float*)d_in[6];
    const float* lb0 = (const float*)d_in[7];
    const float* w1 = (const float*)d_in[8];
    const float* b1 = (const float*)d_in[9];
    const float* g1 = (const float*)d_in[10];
    const float* bb1 = (const float*)d_in[11];
    const float* lw1 = (const float*)d_in[12];
    const float* lb1 = (const float*)d_in[13];
    const float* w2 = (const float*)d_in[14];
    const float* b2 = (const float*)d_in[15];
    const float* g2 = (const float*)d_in[16];
    const float* bb2 = (const float*)d_in[17];
    const float* lw2 = (const float*)d_in[18];
    const float* lb2 = (const float*)d_in[19];
    float* out = (float*)d_out;

    // workspace layout (16B-aligned first)
    char* w = (char*)d_ws;
    int4* ed = (int4*)w;           w += (size_t)N_EDGES * 16;     // 20.48 MB
    float* ybuf = (float*)w;       w += (size_t)N_NODES * 64 * 4; // 20.48 MB
    bf16* hb = (bf16*)w;           w += (size_t)N_NODES * 64 * 2; // 10.24 MB
    int* deg = (int*)w;            w += (size_t)N_NODES * 4;
    float* dinv = (float*)w;       w += (size_t)N_NODES * 4;
    int* cursor = (int*)w;         w += (size_t)N_NODES * 4;
    int* partial = (int*)w;        w += 512 * 4;
    float* bnsum = (float*)w;      w += 384 * 4;
    int* tails = (int*)w;          w += 16 * 4;
    // pairs overlays ybuf (dead until k_h0y); 8*165000*8 B = 10.56 MB <= 20.48 MB
    int2* pairs = (int2*)ybuf;
    // h3 overlays hb (dead after stage-1 agg_es; post64<PROJ> doesn't touch hb)
    float* h3 = (float*)hb;

    const int NB = (N_NODES + 255) / 256;  // 313

    // --- graph/CSR setup (shared by all 3 stages) ---
    k_zero<<<NB, 256, 0, stream>>>(deg, bnsum, tails);
    k_part<<<N_EDGES / EPB, 256, 0, stream>>>(ei, pairs, tails, deg);
    k_scanA<<<NB, 256, 0, stream>>>(deg, partial, dinv);
    k_scanB<<<1, 512, 0, stream>>>(partial, NB);
    k_scanC<<<NB, 256, 0, stream>>>(deg, partial, cursor);
    k_scatter2<<<2048, 256, 0, stream>>>(pairs, tails, dinv, cursor, ed);

    // --- stage 0 ---
    k_h0y<<<(N_NODES * 64 + 255) / 256, 256, 0, stream>>>(x, w0, dinv, b0, hb, ybuf);
    k_agg_es<<<2500, 256, 0, stream>>>(hb, ed, ybuf);
    k_bnstats<<<640, 256, 0, stream>>>(ybuf, bnsum);
    k_post64<1, 0><<<1250, 128, 0, stream>>>(ybuf, bnsum, g0, bb0, lw0, lb0, w1, hb, nullptr);

    // --- stage 1 ---
    k_yinit<<<(N_NODES * 64 + 255) / 256, 256, 0, stream>>>(hb, dinv, b1, ybuf);
    k_agg_es<<<2500, 256, 0, stream>>>(hb, ed, ybuf);
    k_bnstats<<<640, 256, 0, stream>>>(ybuf, bnsum + 128);
    k_post64<2, 1><<<1250, 128, 0, stream>>>(ybuf, bnsum + 128, g1, bb1, lw1, lb1, w2, nullptr, h3);

    // --- stage 2 (C=3) ---
    k_agg3<<<NB, 256, 0, stream>>>(h3, cursor, ed, dinv, b2, ybuf, bnsum + 256);
    k_post3<<<NB, 256, 0, stream>>>(ybuf, bnsum + 256, g2, bb2, lw2, lb2, out);
}